// Round 6
// baseline (380.864 us; speedup 1.0000x reference)
//
#include <hip/hip_runtime.h>
#include <hip/hip_fp16.h>
#include <math.h>

#define NRAY 8192
#define NC_  48
#define NI_  48
#define CPL  32
#define HPL  256
#define HID  64
#define NPTS (NRAY * NC_)        // 393216 points per pass

typedef __attribute__((ext_vector_type(8))) short short8;   // 8 bf16
typedef __attribute__((ext_vector_type(4))) float f32x4;

__device__ __forceinline__ float softplusf(float x) {
    return fmaxf(x, 0.0f) + __logf(1.0f + __expf(-fabsf(x)));
}
__device__ __forceinline__ float sigmoidf(float x) {
    return 1.0f / (1.0f + __expf(-x));
}
__device__ __forceinline__ unsigned short f2bf(float f) {
    unsigned u = __float_as_uint(f);
    u += 0x7fffu + ((u >> 16) & 1u);
    return (unsigned short)(u >> 16);
}

// ---- transpose both (6,32,256,256) fp32 -> interleaved (6,256,256,64) fp16 in one launch ----
__global__ void transpose_cl2(const float* __restrict__ tex, const float* __restrict__ shp,
                              __half* __restrict__ out) {
    __shared__ float tile[32][33];
    int blk = blockIdx.x;          // [0, 24576): p*2048 + y*8 + xt, p in [0,12)
    int xt = blk & 7;
    int y  = (blk >> 3) & 255;
    int p  = blk >> 11;
    const float* in = (p < 6) ? tex : shp;
    int pp    = (p < 6) ? p : p - 6;
    int choff = (p < 6) ? 0 : 32;
    int tx = threadIdx.x;          // 0..31
    int ty = threadIdx.y;          // 0..7
#pragma unroll
    for (int i = 0; i < 4; ++i) {
        int c = ty + 8 * i;
        tile[c][tx] = in[((pp * 32 + c) * 256 + y) * 256 + xt * 32 + tx];
    }
    __syncthreads();
#pragma unroll
    for (int i = 0; i < 4; ++i) {
        int xl = ty + 8 * i;
        out[(size_t)(((pp * 256 + y) * 256) + xt * 32 + xl) * 64 + choff + tx] = __float2half(tile[tx][xl]);
    }
}

__global__ void fill_depths_c(const float* __restrict__ noise, float* __restrict__ depths) {
    int gid = blockIdx.x * blockDim.x + threadIdx.x;
    if (gid >= NPTS) return;
    int s = gid % NC_;
    const float delta = (1.0f - 0.1f) / (NC_ - 1);
    depths[gid] = 0.1f + delta * (float)s + noise[gid] * delta;
}

// ---- one-time weight fragment prep (1 wave) + minmax init ----
__global__ __launch_bounds__(64) void prep_weights(
    const float* __restrict__ W1, const float* __restrict__ b1, const float* __restrict__ W2,
    unsigned short* __restrict__ w1f, float* __restrict__ w2f, float* __restrict__ b1f,
    float* __restrict__ minmax)
{
    int l = threadIdx.x;
    int g = l >> 4, c = l & 15;
    if (l == 0) {
        ((int*)minmax)[0] = 0x7f800000;   // +inf
        ((int*)minmax)[1] = 0xff800000;   // -inf
    }
#pragma unroll
    for (int t = 0; t < 4; ++t) {
#pragma unroll
        for (int kb = 0; kb < 2; ++kb)
#pragma unroll
            for (int j = 0; j < 8; ++j)
                w1f[((t * 2 + kb) * 64 + l) * 8 + j] = f2bf(W1[(kb * 32 + g * 8 + j) * HID + t * 16 + c]);
#pragma unroll
        for (int o = 0; o < 4; ++o) w2f[(t * 64 + l) * 4 + o] = W2[(t * 16 + c) * 4 + o];
        b1f[t * 64 + l] = b1[t * 16 + c];
    }
}

// ---- fused plane-gather + MFMA MLP ----
// Block = 64 adjacent rays at ONE depth slice (tight spatial cluster).
// XCD-slab swizzle: xcd = blockIdx&7 owns rays [xcd*1024, (xcd+1)*1024) across all depths,
// so each per-XCD L2 fetches only its slab's plane region (kills cross-XCD HBM duplication).
__global__ __launch_bounds__(256) void fused_sample_mlp(
    const __half* __restrict__ planes,     // (6,256,256,64) interleaved fp16
    const float* __restrict__ origins, const float* __restrict__ dirs,
    const float* __restrict__ depths,      // [ray][48]
    const unsigned short* __restrict__ w1f, const float* __restrict__ w2f,
    const float* __restrict__ b1f, const float* __restrict__ b2,
    float4* __restrict__ outRGBS)          // [ray][48]
{
    __shared__ unsigned short lds_x[64][72];   // row stride 72 halves: 16B-aligned, 2-way-max banks

    int bid = blockIdx.x;                  // [0, 6144)
    int xcd = bid & 7;
    int iw  = bid >> 3;                    // [0, 768)
    int rg  = iw / 48;                     // ray group within slab [0,16)
    int dsl = iw - rg * 48;                // depth slice [0,48)
    int rayBase = (xcd * 16 + rg) << 6;    // 64-ray group base

    int tid = threadIdx.x;
    // ---------------- gather phase: 4 threads per point(=ray here), 16 channels each ----------------
    {
        int pl = tid >> 2, sub = tid & 3;
        int ray = rayBase + pl;
        int point = ray * NC_ + dsl;
        int bIdx = ray >> 12;

        float ox = origins[ray * 3 + 0], oy = origins[ray * 3 + 1], oz = origins[ray * 3 + 2];
        float dx = dirs[ray * 3 + 0], dy = dirs[ray * 3 + 1], dz = dirs[ray * 3 + 2];
        float invn = 1.0f / sqrtf(dx * dx + dy * dy + dz * dz);
        dx *= invn; dy *= invn; dz *= invn;
        float t = depths[point];
        float px = ox + t * dx, py = oy + t * dy, pz = oz + t * dz;

        float U[3] = {px, px, pz};
        float V[3] = {py, pz, px};

        int   tapOff[12];
        float tapW[12];
        const float inv3 = 1.0f / 3.0f;
#pragma unroll
        for (int pp = 0; pp < 3; ++pp) {
            float gx = (U[pp] + 1.0f) * 128.0f - 0.5f;
            float gy = (V[pp] + 1.0f) * 128.0f - 0.5f;
            float fgx = floorf(gx), fgy = floorf(gy);
            int x0 = (int)fgx, y0 = (int)fgy;
            float fx = gx - fgx, fy = gy - fgy;
#pragma unroll
            for (int k = 0; k < 4; ++k) {
                int dxk = k & 1, dyk = k >> 1;
                int xi = x0 + dxk, yi = y0 + dyk;
                float w = (dxk ? fx : 1.0f - fx) * (dyk ? fy : 1.0f - fy);
                bool valid = (xi >= 0) && (xi < HPL) && (yi >= 0) && (yi < HPL);
                int xc = min(max(xi, 0), HPL - 1);
                int yc = min(max(yi, 0), HPL - 1);
                int p3 = bIdx * 3 + pp;
                tapOff[pp * 4 + k] = (((p3 * HPL) + yc) * HPL + xc) * 64;
                tapW[pp * 4 + k]   = valid ? w * inv3 : 0.0f;
            }
        }

        float acc[16];
#pragma unroll
        for (int i = 0; i < 16; ++i) acc[i] = 0.0f;
#pragma unroll
        for (int kk = 0; kk < 12; ++kk) {
            float w = tapW[kk];
            const float4* pr = (const float4*)(planes + tapOff[kk] + sub * 16);
            float4 v0 = pr[0], v1 = pr[1];
            union { float4 f; __half2 h[4]; } u0, u1;
            u0.f = v0; u1.f = v1;
#pragma unroll
            for (int i = 0; i < 4; ++i) {
                float2 f0 = __half22float2(u0.h[i]);
                float2 f1 = __half22float2(u1.h[i]);
                acc[2 * i]         = fmaf(w, f0.x, acc[2 * i]);
                acc[2 * i + 1]     = fmaf(w, f0.y, acc[2 * i + 1]);
                acc[8 + 2 * i]     = fmaf(w, f1.x, acc[8 + 2 * i]);
                acc[8 + 2 * i + 1] = fmaf(w, f1.y, acc[8 + 2 * i + 1]);
            }
        }
        unsigned short u16[16];
#pragma unroll
        for (int i = 0; i < 16; ++i) u16[i] = f2bf(acc[i]);
        uint4* dst = (uint4*)&lds_x[pl][sub * 16];
        dst[0] = *(uint4*)(u16);
        dst[1] = *(uint4*)(u16 + 8);
    }
    __syncthreads();

    // ---------------- MFMA MLP phase: each wave owns its 16 rows ----------------
    int lane = tid & 63, wave = tid >> 6;
    int g = lane >> 4, c = lane & 15;

    short8 bfr[4][2];
#pragma unroll
    for (int t = 0; t < 4; ++t)
#pragma unroll
        for (int kb = 0; kb < 2; ++kb)
            bfr[t][kb] = *(const short8*)(w1f + ((size_t)((t * 2 + kb) * 64 + lane)) * 8);
    float4 w2v[4];
    float  b1v[4];
#pragma unroll
    for (int t = 0; t < 4; ++t) {
        w2v[t] = *(const float4*)(w2f + (size_t)(t * 64 + lane) * 4);
        b1v[t] = b1f[t * 64 + lane];
    }

    int mrow = wave * 16 + c;
    short8 a0 = *(const short8*)(&lds_x[mrow][g * 8]);
    short8 a1 = *(const short8*)(&lds_x[mrow][32 + g * 8]);

    f32x4 accv[4];
#pragma unroll
    for (int t = 0; t < 4; ++t) {
        f32x4 z = {0.f, 0.f, 0.f, 0.f};
        z = __builtin_amdgcn_mfma_f32_16x16x32_bf16(a0, bfr[t][0], z, 0, 0, 0);
        z = __builtin_amdgcn_mfma_f32_16x16x32_bf16(a1, bfr[t][1], z, 0, 0, 0);
        accv[t] = z;
    }

    float o[4][4];
#pragma unroll
    for (int r = 0; r < 4; ++r)
#pragma unroll
        for (int q = 0; q < 4; ++q) o[r][q] = 0.0f;
#pragma unroll
    for (int t = 0; t < 4; ++t)
#pragma unroll
        for (int r = 0; r < 4; ++r) {
            float h = accv[t][r] + b1v[t];
            float sp = softplusf(h);
            o[r][0] = fmaf(sp, w2v[t].x, o[r][0]);
            o[r][1] = fmaf(sp, w2v[t].y, o[r][1]);
            o[r][2] = fmaf(sp, w2v[t].z, o[r][2]);
            o[r][3] = fmaf(sp, w2v[t].w, o[r][3]);
        }
#pragma unroll
    for (int mask = 1; mask <= 8; mask <<= 1)
#pragma unroll
        for (int r = 0; r < 4; ++r)
#pragma unroll
            for (int q = 0; q < 4; ++q) o[r][q] += __shfl_xor(o[r][q], mask, 64);

    if (c == 0) {
#pragma unroll
        for (int r = 0; r < 4; ++r) {
            int localRow = wave * 16 + g * 4 + r;
            int pt = (rayBase + localRow) * NC_ + dsl;
            float sig = o[r][0] + b2[0];
            float rr = sigmoidf(o[r][1] + b2[1]) * 1.002f - 0.001f;
            float gg = sigmoidf(o[r][2] + b2[2]) * 1.002f - 0.001f;
            float bb = sigmoidf(o[r][3] + b2[3]) * 1.002f - 0.001f;
            outRGBS[pt] = make_float4(rr, gg, bb, sig);
        }
    }
}

// ---- coarse march -> cdf + z_mid per ray, ONE WAVE PER RAY (shuffle scans) ----
// cdfzm row stride 96: [0..45]=cdf, [46..92]=z_mid. Also accumulates global depth min/max.
#define CB_WAVES 4
__global__ __launch_bounds__(256) void cdf_build(
    const float* __restrict__ depths_c, const float4* __restrict__ rgbs_c,
    float* __restrict__ cdfzm, float* __restrict__ minmax)
{
    __shared__ float smn[CB_WAVES], smx[CB_WAVES];
    int wave = threadIdx.x >> 6, lane = threadIdx.x & 63;
    int ray = blockIdx.x * CB_WAVES + wave;

    float d = 0.f, sg = 0.f;
    if (lane < NC_) {
        d  = depths_c[ray * NC_ + lane];
        sg = rgbs_c[ray * NC_ + lane].w;
    }
    float dn = __shfl_down(d, 1, 64);
    float sn = __shfl_down(sg, 1, 64);
    bool iv = (lane < NC_ - 1);            // interval lanes 0..46

    float zm = 0.5f * (d + dn);
    float alpha = 0.f, f = 1.0f;
    if (iv) {
        float dens = softplusf(0.5f * (sg + sn) - 1.0f);
        alpha = 1.0f - __expf(-dens * (dn - d));
        f = 1.0f - alpha + 1e-10f;
    }
    // exclusive prefix product of f
    float x = f;
#pragma unroll
    for (int s = 1; s < 64; s <<= 1) {
        float t = __shfl_up(x, s, 64);
        if (lane >= s) x *= t;
    }
    float excl = __shfl_up(x, 1, 64);
    if (lane == 0) excl = 1.0f;
    float w = alpha * excl;                // weights, lanes 0..46

    float wprev = __shfl_up(w, 1, 64);
    float wmax;                            // lanes 0..47
    if (lane == 0) wmax = w;
    else if (lane == NC_ - 1) wmax = wprev;
    else wmax = fmaxf(wprev, w);
    float wmaxn = __shfl_down(wmax, 1, 64);
    float wb = 0.5f * (wmax + wmaxn) + 0.01f;   // lanes 0..46

    float v = (lane >= 1 && lane <= 45) ? wb : 0.0f;
    float s = v;
#pragma unroll
    for (int mask = 1; mask <= 32; mask <<= 1) s += __shfl_xor(s, mask, 64);
    float pdf = v / s;
    float cum = pdf;
#pragma unroll
    for (int st = 1; st < 64; st <<= 1) {
        float t = __shfl_up(cum, st, 64);
        if (lane >= st) cum += t;
    }
    float* row = cdfzm + (size_t)ray * 96;
    if (lane <= 45) row[lane] = (lane == 0) ? 0.0f : cum;
    if (iv) row[46 + lane] = zm;

    // global min (d at lane 0) / max (d at lane 47)
    float d47 = __shfl(d, NC_ - 1, 64);
    if (lane == 0) { smn[wave] = d; smx[wave] = d47; }
    __syncthreads();
    if (threadIdx.x == 0) {
        float mn = smn[0], mx = smx[0];
#pragma unroll
        for (int i = 1; i < CB_WAVES; ++i) { mn = fminf(mn, smn[i]); mx = fmaxf(mx, smx[i]); }
        atomicMin((int*)minmax, __float_as_int(mn));
        atomicMax(((int*)minmax) + 1, __float_as_int(mx));
    }
}

// ---- importance sampling: one thread per (ray, q) ----
__global__ void imp_sample(const float* __restrict__ cdfzm,
                           const float* __restrict__ impu,
                           float* __restrict__ depths_f)
{
    int gid = blockIdx.x * blockDim.x + threadIdx.x;
    if (gid >= NRAY * NI_) return;
    int ray = gid / NI_;
    const float* cdf = cdfzm + (size_t)ray * 96;
    const float* zm  = cdf + 46;
    float u = impu[gid];
    int lo = 0, hi = 46;
    while (lo < hi) { int mid = (lo + hi) >> 1; if (cdf[mid] > u) hi = mid; else lo = mid + 1; }
    int below = max(lo - 1, 0);
    int above = min(lo, 45);
    float c0 = cdf[below], c1 = cdf[above];
    float b0 = zm[below], b1v = zm[above];
    float den = c1 - c0; if (den < 1e-5f) den = 1.0f;
    depths_f[gid] = b0 + (u - c0) / den * (b1v - b0);
}

// ---- merge + final march: ONE WAVE PER RAY, lane-parallel rank-merge + scan ----
#define FM_WAVES 4
__global__ __launch_bounds__(256) void final_march(
    const float* __restrict__ depths_c, const float4* __restrict__ rgbs_c,
    const float* __restrict__ depths_f, const float4* __restrict__ rgbs_f,
    const float* __restrict__ minmax, float* __restrict__ out)
{
    __shared__ float s_dc[FM_WAVES][NC_];
    __shared__ float s_df[FM_WAVES][NI_];
    __shared__ float s_md[FM_WAVES][96];
    __shared__ float s_ms[FM_WAVES][96];
    __shared__ float s_mr[FM_WAVES][96];
    __shared__ float s_mg[FM_WAVES][96];
    __shared__ float s_mb[FM_WAVES][96];

    int wave = threadIdx.x >> 6, lane = threadIdx.x & 63;
    int ray = blockIdx.x * FM_WAVES + wave;
    float* dcp = s_dc[wave];
    float* dfp = s_df[wave];
    float* mdp = s_md[wave];
    float* msp = s_ms[wave];
    float* mrp = s_mr[wave];
    float* mgp = s_mg[wave];
    float* mbp = s_mb[wave];

    float dcv = 0.f, dfv = 0.f;
    float4 c4 = make_float4(0, 0, 0, 0), f4 = make_float4(0, 0, 0, 0);
    if (lane < NC_) {
        dcv = depths_c[ray * NC_ + lane];
        dfv = depths_f[ray * NI_ + lane];
        dcp[lane] = dcv;
        dfp[lane] = dfv;
        c4 = rgbs_c[ray * NC_ + lane];
        f4 = rgbs_f[ray * NI_ + lane];
    }
    __syncthreads();

    if (lane < NC_) {
        int cntC = 0, rankF = 0, cntCle = 0;
#pragma unroll
        for (int j = 0; j < NC_; ++j) {
            float dfj = dfp[j];
            float dcj = dcp[j];
            cntC   += (dfj < dcv) ? 1 : 0;
            rankF  += ((dfj < dfv) || (dfj == dfv && j < lane)) ? 1 : 0;
            cntCle += (dcj <= dfv) ? 1 : 0;
        }
        int posC = lane + cntC;          // stable: coarse before equal fine
        int posF = rankF + cntCle;
        mdp[posC] = dcv; msp[posC] = c4.w; mrp[posC] = c4.x; mgp[posC] = c4.y; mbp[posC] = c4.z;
        mdp[posF] = dfv; msp[posF] = f4.w; mrp[posF] = f4.x; mgp[posF] = f4.y; mbp[posF] = f4.z;
    }
    __syncthreads();

    int k0 = 2 * lane;
    int i0 = min(k0, 95), i1 = min(k0 + 1, 95), i2 = min(k0 + 2, 95);
    float d0 = mdp[i0], d1 = mdp[i1], d2 = mdp[i2];
    float sg0 = msp[i0], sg1 = msp[i1], sg2 = msp[i2];
    float r0 = mrp[i0], r1 = mrp[i1], r2 = mrp[i2];
    float g0 = mgp[i0], g1 = mgp[i1], g2 = mgp[i2];
    float bb0 = mbp[i0], bb1 = mbp[i1], bb2 = mbp[i2];

    bool v0 = (k0 < 95), v1 = (k0 + 1 < 95);
    float a0 = 0.f, a1 = 0.f, f0 = 1.f, f1 = 1.f;
    if (v0) {
        float dens = softplusf(0.5f * (sg0 + sg1) - 1.0f);
        a0 = 1.0f - __expf(-dens * (d1 - d0));
        f0 = 1.0f - a0 + 1e-10f;
    }
    if (v1) {
        float dens = softplusf(0.5f * (sg1 + sg2) - 1.0f);
        a1 = 1.0f - __expf(-dens * (d2 - d1));
        f1 = 1.0f - a1 + 1e-10f;
    }

    float pl = f0 * f1;
    float x = pl;
#pragma unroll
    for (int d = 1; d < 64; d <<= 1) {
        float t = __shfl_up(x, d, 64);
        if (lane >= d) x *= t;
    }
    float excl = __shfl_up(x, 1, 64);
    if (lane == 0) excl = 1.0f;
    float w0 = a0 * excl;
    float w1 = a1 * excl * f0;

    float accR = w0 * 0.5f * (r0 + r1) + w1 * 0.5f * (r1 + r2);
    float accG = w0 * 0.5f * (g0 + g1) + w1 * 0.5f * (g1 + g2);
    float accB = w0 * 0.5f * (bb0 + bb1) + w1 * 0.5f * (bb1 + bb2);
    float accD = w0 * 0.5f * (d0 + d1) + w1 * 0.5f * (d1 + d2);
    float accW = w0 + w1;
#pragma unroll
    for (int mask = 1; mask <= 32; mask <<= 1) {
        accR += __shfl_xor(accR, mask, 64);
        accG += __shfl_xor(accG, mask, 64);
        accB += __shfl_xor(accB, mask, 64);
        accD += __shfl_xor(accD, mask, 64);
        accW += __shfl_xor(accW, mask, 64);
    }

    if (lane == 0) {
        float q = accD / accW;
        if (!isfinite(q)) q = 0.0f;
        q = fminf(fmaxf(q, minmax[0]), minmax[1]);
        out[ray * 3 + 0] = accR * 2.0f - 1.0f;
        out[ray * 3 + 1] = accG * 2.0f - 1.0f;
        out[ray * 3 + 2] = accB * 2.0f - 1.0f;
        out[3 * NRAY + ray] = q;
        out[4 * NRAY + ray] = accW;
    }
}

extern "C" void kernel_launch(void* const* d_in, const int* in_sizes, int n_in,
                              void* d_out, int out_size, void* d_ws, size_t ws_size,
                              hipStream_t stream)
{
    const float* planes_tex = (const float*)d_in[0];
    const float* planes_shp = (const float*)d_in[1];
    const float* origins    = (const float*)d_in[2];
    const float* raydirs    = (const float*)d_in[3];
    const float* W1 = (const float*)d_in[4];
    const float* b1 = (const float*)d_in[5];
    const float* W2 = (const float*)d_in[6];
    const float* b2 = (const float*)d_in[7];
    const float* noise = (const float*)d_in[8];
    const float* impu  = (const float*)d_in[9];
    float* out = (float*)d_out;

    char* ws = (char*)d_ws;
    __half*         planes_cl = (__half*)ws;                          // 50,331,648 B
    unsigned short* w1f       = (unsigned short*)(ws + 50331648);     // 8,192 B
    float*          w2f       = (float*)(ws + 50339840);              // 4,096 B
    float*          b1f       = (float*)(ws + 50343936);              // 1,024 B
    float*          cdfzm     = (float*)(ws + 50348032);              // 3,145,728 B
    float*          minmax    = (float*)(ws + 53493760);              // 8 B (+pad)
    float*  depths_c = (float*)(ws + 53494016);                       // 1,572,864 B
    float*  depths_f = depths_c + NPTS;                               // 1,572,864 B
    float4* rgbs_c   = (float4*)(depths_f + NPTS);                    // 6,291,456 B
    float4* rgbs_f   = rgbs_c + NPTS;                                 // 6,291,456 B

    dim3 tb(32, 8);
    transpose_cl2<<<dim3(12 * 256 * 8), tb, 0, stream>>>(planes_tex, planes_shp, planes_cl);
    prep_weights<<<dim3(1), dim3(64), 0, stream>>>(W1, b1, W2, w1f, w2f, b1f, minmax);
    fill_depths_c<<<dim3((NPTS + 255) / 256), dim3(256), 0, stream>>>(noise, depths_c);

    fused_sample_mlp<<<dim3(NPTS / 64), dim3(256), 0, stream>>>(
        planes_cl, origins, raydirs, depths_c, w1f, w2f, b1f, b2, rgbs_c);

    cdf_build<<<dim3(NRAY / CB_WAVES), dim3(256), 0, stream>>>(depths_c, rgbs_c, cdfzm, minmax);
    imp_sample<<<dim3((NRAY * NI_ + 255) / 256), dim3(256), 0, stream>>>(cdfzm, impu, depths_f);

    fused_sample_mlp<<<dim3(NPTS / 64), dim3(256), 0, stream>>>(
        planes_cl, origins, raydirs, depths_f, w1f, w2f, b1f, b2, rgbs_f);

    final_march<<<dim3(NRAY / FM_WAVES), dim3(256), 0, stream>>>(depths_c, rgbs_c, depths_f, rgbs_f, minmax, out);
}

// Round 7
// 362.407 us; speedup vs baseline: 1.0509x; 1.0509x over previous
//
#include <hip/hip_runtime.h>
#include <hip/hip_fp16.h>
#include <math.h>

#define NRAY 8192
#define NC_  48
#define NI_  48
#define CPL  32
#define HPL  256
#define HID  64
#define NPTS (NRAY * NC_)        // 393216 points per pass

typedef __attribute__((ext_vector_type(8))) short short8;   // 8 bf16
typedef __attribute__((ext_vector_type(4))) float f32x4;

__device__ __forceinline__ float softplusf(float x) {
    return fmaxf(x, 0.0f) + __logf(1.0f + __expf(-fabsf(x)));
}
__device__ __forceinline__ float sigmoidf(float x) {
    return 1.0f / (1.0f + __expf(-x));
}
__device__ __forceinline__ unsigned short f2bf(float f) {
    unsigned u = __float_as_uint(f);
    u += 0x7fffu + ((u >> 16) & 1u);
    return (unsigned short)(u >> 16);
}

// ================= setup mega-kernel =================
// blocks [0, 24576): transpose both plane tensors -> interleaved (6,256,256,64) fp16
// block  24576     : weight fragment prep + minmax init
// blocks (24576, 26113): fill depths_c
#define TR_BLOCKS 24576
__global__ __launch_bounds__(256) void setup_kernel(
    const float* __restrict__ tex, const float* __restrict__ shp,
    __half* __restrict__ planes_cl,
    const float* __restrict__ W1, const float* __restrict__ b1, const float* __restrict__ W2,
    unsigned short* __restrict__ w1f, float* __restrict__ w2f, float* __restrict__ b1f,
    float* __restrict__ minmax,
    const float* __restrict__ noise, float* __restrict__ depths)
{
    int b = blockIdx.x;
    if (b < TR_BLOCKS) {
        __shared__ float tile[32][33];
        int xt = b & 7;
        int y  = (b >> 3) & 255;
        int p  = b >> 11;                 // [0,12)
        const float* in = (p < 6) ? tex : shp;
        int pp    = (p < 6) ? p : p - 6;
        int choff = (p < 6) ? 0 : 32;
        int tx = threadIdx.x & 31;
        int ty = threadIdx.x >> 5;        // 0..7
#pragma unroll
        for (int i = 0; i < 4; ++i) {
            int c = ty + 8 * i;
            tile[c][tx] = in[((pp * 32 + c) * 256 + y) * 256 + xt * 32 + tx];
        }
        __syncthreads();
#pragma unroll
        for (int i = 0; i < 4; ++i) {
            int xl = ty + 8 * i;
            planes_cl[(size_t)(((pp * 256 + y) * 256) + xt * 32 + xl) * 64 + choff + tx] =
                __float2half(tile[tx][xl]);
        }
    } else if (b == TR_BLOCKS) {
        int l = threadIdx.x;
        if (l == 0) {
            ((int*)minmax)[0] = 0x7f800000;   // +inf
            ((int*)minmax)[1] = 0xff800000;   // -inf
        }
        if (l < 64) {
            int g = l >> 4, c = l & 15;
#pragma unroll
            for (int t = 0; t < 4; ++t) {
#pragma unroll
                for (int kb = 0; kb < 2; ++kb)
#pragma unroll
                    for (int j = 0; j < 8; ++j)
                        w1f[((t * 2 + kb) * 64 + l) * 8 + j] =
                            f2bf(W1[(kb * 32 + g * 8 + j) * HID + t * 16 + c]);
#pragma unroll
                for (int o = 0; o < 4; ++o) w2f[(t * 64 + l) * 4 + o] = W2[(t * 16 + c) * 4 + o];
                b1f[t * 64 + l] = b1[t * 16 + c];
            }
        }
    } else {
        int gid = (b - TR_BLOCKS - 1) * 256 + threadIdx.x;
        if (gid < NPTS) {
            int s = gid % NC_;
            const float delta = (1.0f - 0.1f) / (NC_ - 1);
            depths[gid] = 0.1f + delta * (float)s + noise[gid] * delta;
        }
    }
}

// ================= fused plane-gather + MFMA MLP =================
// Block = 64 consecutive points (point-major: same-ray adjacent depths share texture lines).
// Phase A: 64 threads compute the 12 taps once per point -> LDS.
// Phase B: 4 threads/point x 16 channels gather+accumulate -> LDS features.
// Phase C: wave-per-16-points MFMA MLP.
__global__ __launch_bounds__(256) void fused_sample_mlp(
    const __half* __restrict__ planes,     // (6,256,256,64) interleaved fp16
    const float* __restrict__ origins, const float* __restrict__ dirs,
    const float* __restrict__ depths,      // [point]
    const unsigned short* __restrict__ w1f, const float* __restrict__ w2f,
    const float* __restrict__ b1f, const float* __restrict__ b2,
    float4* __restrict__ outRGBS)          // [point]
{
    __shared__ unsigned short lds_x[64][72];   // feature rows, stride 72 halves
    __shared__ int   s_tapOff[64][12];
    __shared__ float s_tapW[64][12];

    int tid = threadIdx.x;

    // ---------------- phase A: taps once per point ----------------
    if (tid < 64) {
        int point = blockIdx.x * 64 + tid;
        int ray = point / NC_;
        int bIdx = ray >> 12;

        float ox = origins[ray * 3 + 0], oy = origins[ray * 3 + 1], oz = origins[ray * 3 + 2];
        float dx = dirs[ray * 3 + 0], dy = dirs[ray * 3 + 1], dz = dirs[ray * 3 + 2];
        float invn = 1.0f / sqrtf(dx * dx + dy * dy + dz * dz);
        dx *= invn; dy *= invn; dz *= invn;
        float t = depths[point];
        float px = ox + t * dx, py = oy + t * dy, pz = oz + t * dz;

        float U[3] = {px, px, pz};
        float V[3] = {py, pz, px};
        const float inv3 = 1.0f / 3.0f;
#pragma unroll
        for (int pp = 0; pp < 3; ++pp) {
            float gx = (U[pp] + 1.0f) * 128.0f - 0.5f;
            float gy = (V[pp] + 1.0f) * 128.0f - 0.5f;
            float fgx = floorf(gx), fgy = floorf(gy);
            int x0 = (int)fgx, y0 = (int)fgy;
            float fx = gx - fgx, fy = gy - fgy;
#pragma unroll
            for (int k = 0; k < 4; ++k) {
                int dxk = k & 1, dyk = k >> 1;
                int xi = x0 + dxk, yi = y0 + dyk;
                float w = (dxk ? fx : 1.0f - fx) * (dyk ? fy : 1.0f - fy);
                bool valid = (xi >= 0) && (xi < HPL) && (yi >= 0) && (yi < HPL);
                int xc = min(max(xi, 0), HPL - 1);
                int yc = min(max(yi, 0), HPL - 1);
                int p3 = bIdx * 3 + pp;
                s_tapOff[tid][pp * 4 + k] = (((p3 * HPL) + yc) * HPL + xc) * 64;
                s_tapW[tid][pp * 4 + k]   = valid ? w * inv3 : 0.0f;
            }
        }
    }
    __syncthreads();

    // ---------------- phase B: gather, 4 threads/point ----------------
    {
        int pl = tid >> 2, sub = tid & 3;
        float acc[16];
#pragma unroll
        for (int i = 0; i < 16; ++i) acc[i] = 0.0f;
#pragma unroll
        for (int kk = 0; kk < 12; ++kk) {
            float w  = s_tapW[pl][kk];
            int  off = s_tapOff[pl][kk];
            const float4* pr = (const float4*)(planes + off + sub * 16);
            float4 v0 = pr[0], v1 = pr[1];
            union { float4 f; __half2 h[4]; } u0, u1;
            u0.f = v0; u1.f = v1;
#pragma unroll
            for (int i = 0; i < 4; ++i) {
                float2 f0 = __half22float2(u0.h[i]);
                float2 f1 = __half22float2(u1.h[i]);
                acc[2 * i]         = fmaf(w, f0.x, acc[2 * i]);
                acc[2 * i + 1]     = fmaf(w, f0.y, acc[2 * i + 1]);
                acc[8 + 2 * i]     = fmaf(w, f1.x, acc[8 + 2 * i]);
                acc[8 + 2 * i + 1] = fmaf(w, f1.y, acc[8 + 2 * i + 1]);
            }
        }
        unsigned short u16[16];
#pragma unroll
        for (int i = 0; i < 16; ++i) u16[i] = f2bf(acc[i]);
        uint4* dst = (uint4*)&lds_x[pl][sub * 16];
        dst[0] = *(uint4*)(u16);
        dst[1] = *(uint4*)(u16 + 8);
    }
    __syncthreads();

    // ---------------- phase C: MFMA MLP ----------------
    int lane = tid & 63, wave = tid >> 6;
    int g = lane >> 4, c = lane & 15;
    int m0 = blockIdx.x * 64 + wave * 16;

    short8 bfr[4][2];
#pragma unroll
    for (int t = 0; t < 4; ++t)
#pragma unroll
        for (int kb = 0; kb < 2; ++kb)
            bfr[t][kb] = *(const short8*)(w1f + ((size_t)((t * 2 + kb) * 64 + lane)) * 8);
    float4 w2v[4];
    float  b1v[4];
#pragma unroll
    for (int t = 0; t < 4; ++t) {
        w2v[t] = *(const float4*)(w2f + (size_t)(t * 64 + lane) * 4);
        b1v[t] = b1f[t * 64 + lane];
    }

    int mrow = wave * 16 + c;
    short8 a0 = *(const short8*)(&lds_x[mrow][g * 8]);
    short8 a1 = *(const short8*)(&lds_x[mrow][32 + g * 8]);

    f32x4 accv[4];
#pragma unroll
    for (int t = 0; t < 4; ++t) {
        f32x4 z = {0.f, 0.f, 0.f, 0.f};
        z = __builtin_amdgcn_mfma_f32_16x16x32_bf16(a0, bfr[t][0], z, 0, 0, 0);
        z = __builtin_amdgcn_mfma_f32_16x16x32_bf16(a1, bfr[t][1], z, 0, 0, 0);
        accv[t] = z;
    }

    float o[4][4];
#pragma unroll
    for (int r = 0; r < 4; ++r)
#pragma unroll
        for (int q = 0; q < 4; ++q) o[r][q] = 0.0f;
#pragma unroll
    for (int t = 0; t < 4; ++t)
#pragma unroll
        for (int r = 0; r < 4; ++r) {
            float h = accv[t][r] + b1v[t];
            float sp = softplusf(h);
            o[r][0] = fmaf(sp, w2v[t].x, o[r][0]);
            o[r][1] = fmaf(sp, w2v[t].y, o[r][1]);
            o[r][2] = fmaf(sp, w2v[t].z, o[r][2]);
            o[r][3] = fmaf(sp, w2v[t].w, o[r][3]);
        }
#pragma unroll
    for (int mask = 1; mask <= 8; mask <<= 1)
#pragma unroll
        for (int r = 0; r < 4; ++r)
#pragma unroll
            for (int q = 0; q < 4; ++q) o[r][q] += __shfl_xor(o[r][q], mask, 64);

    if (c == 0) {
#pragma unroll
        for (int r = 0; r < 4; ++r) {
            int pt = m0 + g * 4 + r;
            float sig = o[r][0] + b2[0];
            float rr = sigmoidf(o[r][1] + b2[1]) * 1.002f - 0.001f;
            float gg = sigmoidf(o[r][2] + b2[2]) * 1.002f - 0.001f;
            float bb = sigmoidf(o[r][3] + b2[3]) * 1.002f - 0.001f;
            outRGBS[pt] = make_float4(rr, gg, bb, sig);
        }
    }
}

// ========== coarse march -> cdf (shuffle scans) -> importance sample, fused ==========
#define CI_WAVES 4
__global__ __launch_bounds__(256) void cdf_imp(
    const float* __restrict__ depths_c, const float4* __restrict__ rgbs_c,
    const float* __restrict__ impu,
    float* __restrict__ depths_f, float* __restrict__ minmax)
{
    __shared__ float s_cdf[CI_WAVES][48];   // [0..45] cdf
    __shared__ float s_zm[CI_WAVES][48];    // [0..46] z_mid
    __shared__ float smn[CI_WAVES], smx[CI_WAVES];
    int wave = threadIdx.x >> 6, lane = threadIdx.x & 63;
    int ray = blockIdx.x * CI_WAVES + wave;

    float d = 0.f, sg = 0.f;
    if (lane < NC_) {
        d  = depths_c[ray * NC_ + lane];
        sg = rgbs_c[ray * NC_ + lane].w;
    }
    float dn = __shfl_down(d, 1, 64);
    float sn = __shfl_down(sg, 1, 64);
    bool iv = (lane < NC_ - 1);            // interval lanes 0..46

    float zm = 0.5f * (d + dn);
    float alpha = 0.f, f = 1.0f;
    if (iv) {
        float dens = softplusf(0.5f * (sg + sn) - 1.0f);
        alpha = 1.0f - __expf(-dens * (dn - d));
        f = 1.0f - alpha + 1e-10f;
    }
    float x = f;
#pragma unroll
    for (int s = 1; s < 64; s <<= 1) {
        float t = __shfl_up(x, s, 64);
        if (lane >= s) x *= t;
    }
    float excl = __shfl_up(x, 1, 64);
    if (lane == 0) excl = 1.0f;
    float w = alpha * excl;                // weights, lanes 0..46

    float wprev = __shfl_up(w, 1, 64);
    float wmax;                            // lanes 0..47
    if (lane == 0) wmax = w;
    else if (lane == NC_ - 1) wmax = wprev;
    else wmax = fmaxf(wprev, w);
    float wmaxn = __shfl_down(wmax, 1, 64);
    float wb = 0.5f * (wmax + wmaxn) + 0.01f;   // lanes 0..46

    float v = (lane >= 1 && lane <= 45) ? wb : 0.0f;
    float s = v;
#pragma unroll
    for (int mask = 1; mask <= 32; mask <<= 1) s += __shfl_xor(s, mask, 64);
    float pdf = v / s;
    float cum = pdf;
#pragma unroll
    for (int st = 1; st < 64; st <<= 1) {
        float t = __shfl_up(cum, st, 64);
        if (lane >= st) cum += t;
    }
    if (lane <= 45) s_cdf[wave][lane] = (lane == 0) ? 0.0f : cum;
    if (iv) s_zm[wave][lane] = zm;

    float d47 = __shfl(d, NC_ - 1, 64);
    if (lane == 0) { smn[wave] = d; smx[wave] = d47; }
    __syncthreads();
    if (threadIdx.x == 0) {
        float mn = smn[0], mx = smx[0];
#pragma unroll
        for (int i = 1; i < CI_WAVES; ++i) { mn = fminf(mn, smn[i]); mx = fmaxf(mx, smx[i]); }
        atomicMin((int*)minmax, __float_as_int(mn));
        atomicMax(((int*)minmax) + 1, __float_as_int(mx));
    }

    // importance sampling: lanes 0..47 each handle one u
    if (lane < NI_) {
        const float* cdf = s_cdf[wave];
        const float* zmp = s_zm[wave];
        float u = impu[ray * NI_ + lane];
        int lo = 0, hi = 46;
        while (lo < hi) { int mid = (lo + hi) >> 1; if (cdf[mid] > u) hi = mid; else lo = mid + 1; }
        int below = max(lo - 1, 0);
        int above = min(lo, 45);
        float c0 = cdf[below], c1 = cdf[above];
        float b0 = zmp[below], b1v = zmp[above];
        float den = c1 - c0; if (den < 1e-5f) den = 1.0f;
        depths_f[ray * NI_ + lane] = b0 + (u - c0) / den * (b1v - b0);
    }
}

// ---- merge + final march: ONE WAVE PER RAY, lane-parallel rank-merge + scan ----
#define FM_WAVES 4
__global__ __launch_bounds__(256) void final_march(
    const float* __restrict__ depths_c, const float4* __restrict__ rgbs_c,
    const float* __restrict__ depths_f, const float4* __restrict__ rgbs_f,
    const float* __restrict__ minmax, float* __restrict__ out)
{
    __shared__ float s_dc[FM_WAVES][NC_];
    __shared__ float s_df[FM_WAVES][NI_];
    __shared__ float s_md[FM_WAVES][96];
    __shared__ float s_ms[FM_WAVES][96];
    __shared__ float s_mr[FM_WAVES][96];
    __shared__ float s_mg[FM_WAVES][96];
    __shared__ float s_mb[FM_WAVES][96];

    int wave = threadIdx.x >> 6, lane = threadIdx.x & 63;
    int ray = blockIdx.x * FM_WAVES + wave;
    float* dcp = s_dc[wave];
    float* dfp = s_df[wave];
    float* mdp = s_md[wave];
    float* msp = s_ms[wave];
    float* mrp = s_mr[wave];
    float* mgp = s_mg[wave];
    float* mbp = s_mb[wave];

    float dcv = 0.f, dfv = 0.f;
    float4 c4 = make_float4(0, 0, 0, 0), f4 = make_float4(0, 0, 0, 0);
    if (lane < NC_) {
        dcv = depths_c[ray * NC_ + lane];
        dfv = depths_f[ray * NI_ + lane];
        dcp[lane] = dcv;
        dfp[lane] = dfv;
        c4 = rgbs_c[ray * NC_ + lane];
        f4 = rgbs_f[ray * NI_ + lane];
    }
    __syncthreads();

    if (lane < NC_) {
        int cntC = 0, rankF = 0, cntCle = 0;
#pragma unroll
        for (int j = 0; j < NC_; ++j) {
            float dfj = dfp[j];
            float dcj = dcp[j];
            cntC   += (dfj < dcv) ? 1 : 0;
            rankF  += ((dfj < dfv) || (dfj == dfv && j < lane)) ? 1 : 0;
            cntCle += (dcj <= dfv) ? 1 : 0;
        }
        int posC = lane + cntC;          // stable: coarse before equal fine
        int posF = rankF + cntCle;
        mdp[posC] = dcv; msp[posC] = c4.w; mrp[posC] = c4.x; mgp[posC] = c4.y; mbp[posC] = c4.z;
        mdp[posF] = dfv; msp[posF] = f4.w; mrp[posF] = f4.x; mgp[posF] = f4.y; mbp[posF] = f4.z;
    }
    __syncthreads();

    int k0 = 2 * lane;
    int i0 = min(k0, 95), i1 = min(k0 + 1, 95), i2 = min(k0 + 2, 95);
    float d0 = mdp[i0], d1 = mdp[i1], d2 = mdp[i2];
    float sg0 = msp[i0], sg1 = msp[i1], sg2 = msp[i2];
    float r0 = mrp[i0], r1 = mrp[i1], r2 = mrp[i2];
    float g0 = mgp[i0], g1 = mgp[i1], g2 = mgp[i2];
    float bb0 = mbp[i0], bb1 = mbp[i1], bb2 = mbp[i2];

    bool v0 = (k0 < 95), v1 = (k0 + 1 < 95);
    float a0 = 0.f, a1 = 0.f, f0 = 1.f, f1 = 1.f;
    if (v0) {
        float dens = softplusf(0.5f * (sg0 + sg1) - 1.0f);
        a0 = 1.0f - __expf(-dens * (d1 - d0));
        f0 = 1.0f - a0 + 1e-10f;
    }
    if (v1) {
        float dens = softplusf(0.5f * (sg1 + sg2) - 1.0f);
        a1 = 1.0f - __expf(-dens * (d2 - d1));
        f1 = 1.0f - a1 + 1e-10f;
    }

    float pl = f0 * f1;
    float x = pl;
#pragma unroll
    for (int d = 1; d < 64; d <<= 1) {
        float t = __shfl_up(x, d, 64);
        if (lane >= d) x *= t;
    }
    float excl = __shfl_up(x, 1, 64);
    if (lane == 0) excl = 1.0f;
    float w0 = a0 * excl;
    float w1 = a1 * excl * f0;

    float accR = w0 * 0.5f * (r0 + r1) + w1 * 0.5f * (r1 + r2);
    float accG = w0 * 0.5f * (g0 + g1) + w1 * 0.5f * (g1 + g2);
    float accB = w0 * 0.5f * (bb0 + bb1) + w1 * 0.5f * (bb1 + bb2);
    float accD = w0 * 0.5f * (d0 + d1) + w1 * 0.5f * (d1 + d2);
    float accW = w0 + w1;
#pragma unroll
    for (int mask = 1; mask <= 32; mask <<= 1) {
        accR += __shfl_xor(accR, mask, 64);
        accG += __shfl_xor(accG, mask, 64);
        accB += __shfl_xor(accB, mask, 64);
        accD += __shfl_xor(accD, mask, 64);
        accW += __shfl_xor(accW, mask, 64);
    }

    if (lane == 0) {
        float q = accD / accW;
        if (!isfinite(q)) q = 0.0f;
        q = fminf(fmaxf(q, minmax[0]), minmax[1]);
        out[ray * 3 + 0] = accR * 2.0f - 1.0f;
        out[ray * 3 + 1] = accG * 2.0f - 1.0f;
        out[ray * 3 + 2] = accB * 2.0f - 1.0f;
        out[3 * NRAY + ray] = q;
        out[4 * NRAY + ray] = accW;
    }
}

extern "C" void kernel_launch(void* const* d_in, const int* in_sizes, int n_in,
                              void* d_out, int out_size, void* d_ws, size_t ws_size,
                              hipStream_t stream)
{
    const float* planes_tex = (const float*)d_in[0];
    const float* planes_shp = (const float*)d_in[1];
    const float* origins    = (const float*)d_in[2];
    const float* raydirs    = (const float*)d_in[3];
    const float* W1 = (const float*)d_in[4];
    const float* b1 = (const float*)d_in[5];
    const float* W2 = (const float*)d_in[6];
    const float* b2 = (const float*)d_in[7];
    const float* noise = (const float*)d_in[8];
    const float* impu  = (const float*)d_in[9];
    float* out = (float*)d_out;

    char* ws = (char*)d_ws;
    __half*         planes_cl = (__half*)ws;                          // 50,331,648 B
    unsigned short* w1f       = (unsigned short*)(ws + 50331648);     // 8,192 B
    float*          w2f       = (float*)(ws + 50339840);              // 4,096 B
    float*          b1f       = (float*)(ws + 50343936);              // 1,024 B
    float*          minmax    = (float*)(ws + 50345216);              // 8 B (+pad)
    float*  depths_c = (float*)(ws + 50345472);                       // 1,572,864 B
    float*  depths_f = depths_c + NPTS;                               // 1,572,864 B
    float4* rgbs_c   = (float4*)(depths_f + NPTS);                    // 6,291,456 B
    float4* rgbs_f   = rgbs_c + NPTS;                                 // 6,291,456 B

    int fill_blocks = (NPTS + 255) / 256;                             // 1536
    setup_kernel<<<dim3(TR_BLOCKS + 1 + fill_blocks), dim3(256), 0, stream>>>(
        planes_tex, planes_shp, planes_cl, W1, b1, W2, w1f, w2f, b1f, minmax, noise, depths_c);

    fused_sample_mlp<<<dim3(NPTS / 64), dim3(256), 0, stream>>>(
        planes_cl, origins, raydirs, depths_c, w1f, w2f, b1f, b2, rgbs_c);

    cdf_imp<<<dim3(NRAY / CI_WAVES), dim3(256), 0, stream>>>(depths_c, rgbs_c, impu, depths_f, minmax);

    fused_sample_mlp<<<dim3(NPTS / 64), dim3(256), 0, stream>>>(
        planes_cl, origins, raydirs, depths_f, w1f, w2f, b1f, b2, rgbs_f);

    final_march<<<dim3(NRAY / FM_WAVES), dim3(256), 0, stream>>>(depths_c, rgbs_c, depths_f, rgbs_f, minmax, out);
}

// Round 8
// 337.293 us; speedup vs baseline: 1.1292x; 1.0745x over previous
//
#include <hip/hip_runtime.h>
#include <hip/hip_fp16.h>
#include <math.h>

#define NRAY 8192
#define NC_  48
#define NI_  48
#define CPL  32
#define HPL  256
#define HID  64
#define NPTS (NRAY * NC_)        // 393216 points per pass

typedef __attribute__((ext_vector_type(8))) short short8;   // 8 bf16
typedef __attribute__((ext_vector_type(4))) float f32x4;

__device__ __forceinline__ float softplusf(float x) {
    return fmaxf(x, 0.0f) + __logf(1.0f + __expf(-fabsf(x)));
}
__device__ __forceinline__ float sigmoidf(float x) {
    return 1.0f / (1.0f + __expf(-x));
}
__device__ __forceinline__ unsigned short f2bf(float f) {
    unsigned u = __float_as_uint(f);
    u += 0x7fffu + ((u >> 16) & 1u);
    return (unsigned short)(u >> 16);
}

// ================= setup mega-kernel =================
#define TR_BLOCKS 24576
__global__ __launch_bounds__(256) void setup_kernel(
    const float* __restrict__ tex, const float* __restrict__ shp,
    __half* __restrict__ planes_cl,
    const float* __restrict__ W1, const float* __restrict__ b1, const float* __restrict__ W2,
    unsigned short* __restrict__ w1f, float* __restrict__ w2f, float* __restrict__ b1f,
    float* __restrict__ minmax,
    const float* __restrict__ noise, float* __restrict__ depths)
{
    int b = blockIdx.x;
    if (b < TR_BLOCKS) {
        __shared__ float tile[32][33];
        int xt = b & 7;
        int y  = (b >> 3) & 255;
        int p  = b >> 11;                 // [0,12)
        const float* in = (p < 6) ? tex : shp;
        int pp    = (p < 6) ? p : p - 6;
        int choff = (p < 6) ? 0 : 32;
        int tx = threadIdx.x & 31;
        int ty = threadIdx.x >> 5;        // 0..7
#pragma unroll
        for (int i = 0; i < 4; ++i) {
            int c = ty + 8 * i;
            tile[c][tx] = in[((pp * 32 + c) * 256 + y) * 256 + xt * 32 + tx];
        }
        __syncthreads();
#pragma unroll
        for (int i = 0; i < 4; ++i) {
            int xl = ty + 8 * i;
            planes_cl[(size_t)(((pp * 256 + y) * 256) + xt * 32 + xl) * 64 + choff + tx] =
                __float2half(tile[tx][xl]);
        }
    } else if (b == TR_BLOCKS) {
        int l = threadIdx.x;
        if (l == 0) {
            ((int*)minmax)[0] = 0x7f800000;   // +inf
            ((int*)minmax)[1] = 0xff800000;   // -inf
        }
        if (l < 64) {
            int g = l >> 4, c = l & 15;
#pragma unroll
            for (int t = 0; t < 4; ++t) {
#pragma unroll
                for (int kb = 0; kb < 2; ++kb)
#pragma unroll
                    for (int j = 0; j < 8; ++j)
                        w1f[((t * 2 + kb) * 64 + l) * 8 + j] =
                            f2bf(W1[(kb * 32 + g * 8 + j) * HID + t * 16 + c]);
#pragma unroll
                for (int o = 0; o < 4; ++o) w2f[(t * 64 + l) * 4 + o] = W2[(t * 16 + c) * 4 + o];
                b1f[t * 64 + l] = b1[t * 16 + c];
            }
        }
    } else {
        int gid = (b - TR_BLOCKS - 1) * 256 + threadIdx.x;
        if (gid < NPTS) {
            int s = gid % NC_;
            const float delta = (1.0f - 0.1f) / (NC_ - 1);
            depths[gid] = 0.1f + delta * (float)s + noise[gid] * delta;
        }
    }
}

// ================= fused plane-gather + MFMA MLP =================
// Block = 32 points. Phase A: 96 threads compute taps (1 thread per point-plane) -> LDS.
// Phase B: 8 threads/point x 8 channels gather -> LDS feature rows (bf16).
// Phase C: waves 0,1 run the MFMA MLP for 16 points each.
// __launch_bounds__(256,8): pin VGPR <= 64 so 8 waves/SIMD can be resident (latency hiding).
__global__ __launch_bounds__(256, 8) void fused_sample_mlp(
    const __half* __restrict__ planes,     // (6,256,256,64) interleaved fp16
    const float* __restrict__ origins, const float* __restrict__ dirs,
    const float* __restrict__ depths,      // [point]
    const unsigned short* __restrict__ w1f, const float* __restrict__ w2f,
    const float* __restrict__ b1f, const float* __restrict__ b2,
    float4* __restrict__ outRGBS)          // [point]
{
    __shared__ unsigned short lds_x[32][72];   // feature rows, stride 72 halves (conflict-free)
    __shared__ int s_tap[32][12][2];           // (off, w-bits) pairs; stride 24 dwords (2-way max)

    int tid = threadIdx.x;

    // ---------------- phase A: 1 thread per (point, plane) ----------------
    if (tid < 96) {
        int p  = tid & 31;
        int pp = tid >> 5;                 // plane 0..2
        int point = blockIdx.x * 32 + p;
        int ray = point / NC_;
        int bIdx = ray >> 12;

        float ox = origins[ray * 3 + 0], oy = origins[ray * 3 + 1], oz = origins[ray * 3 + 2];
        float dx = dirs[ray * 3 + 0], dy = dirs[ray * 3 + 1], dz = dirs[ray * 3 + 2];
        float invn = 1.0f / sqrtf(dx * dx + dy * dy + dz * dz);
        dx *= invn; dy *= invn; dz *= invn;
        float t = depths[point];
        float px = ox + t * dx, py = oy + t * dy, pz = oz + t * dz;

        // projections: p0:(x,y) p1:(x,z) p2:(z,x)
        float U = (pp == 2) ? pz : px;
        float V = (pp == 0) ? py : ((pp == 1) ? pz : px);
        const float inv3 = 1.0f / 3.0f;

        float gx = (U + 1.0f) * 128.0f - 0.5f;
        float gy = (V + 1.0f) * 128.0f - 0.5f;
        float fgx = floorf(gx), fgy = floorf(gy);
        int x0 = (int)fgx, y0 = (int)fgy;
        float fx = gx - fgx, fy = gy - fgy;
#pragma unroll
        for (int k = 0; k < 4; ++k) {
            int dxk = k & 1, dyk = k >> 1;
            int xi = x0 + dxk, yi = y0 + dyk;
            float w = (dxk ? fx : 1.0f - fx) * (dyk ? fy : 1.0f - fy);
            bool valid = (xi >= 0) && (xi < HPL) && (yi >= 0) && (yi < HPL);
            int xc = min(max(xi, 0), HPL - 1);
            int yc = min(max(yi, 0), HPL - 1);
            int p3 = bIdx * 3 + pp;
            s_tap[p][pp * 4 + k][0] = (((p3 * HPL) + yc) * HPL + xc) * 64;
            s_tap[p][pp * 4 + k][1] = __float_as_int(valid ? w * inv3 : 0.0f);
        }
    }
    __syncthreads();

    // ---------------- phase B: 8 threads/point, 8 channels each ----------------
    {
        int p = tid >> 3, sub = tid & 7;
        // hoist all 12 (off, w) pairs first so loads can pipeline
        int   off[12];
        float wv[12];
#pragma unroll
        for (int kk = 0; kk < 12; ++kk) {
            off[kk] = s_tap[p][kk][0];
            wv[kk]  = __int_as_float(s_tap[p][kk][1]);
        }
        float acc[8];
#pragma unroll
        for (int i = 0; i < 8; ++i) acc[i] = 0.0f;
#pragma unroll
        for (int kk = 0; kk < 12; ++kk) {
            float w = wv[kk];
            float4 v = *(const float4*)(planes + off[kk] + sub * 8);
            union { float4 f; __half2 h[4]; } u;
            u.f = v;
#pragma unroll
            for (int i = 0; i < 4; ++i) {
                float2 f2 = __half22float2(u.h[i]);
                acc[2 * i]     = fmaf(w, f2.x, acc[2 * i]);
                acc[2 * i + 1] = fmaf(w, f2.y, acc[2 * i + 1]);
            }
        }
        unsigned short u16[8];
#pragma unroll
        for (int i = 0; i < 8; ++i) u16[i] = f2bf(acc[i]);
        *(uint4*)&lds_x[p][sub * 8] = *(uint4*)(u16);
    }
    __syncthreads();

    // ---------------- phase C: waves 0,1 -> MFMA MLP, 16 points each ----------------
    int lane = tid & 63, wave = tid >> 6;
    if (wave < 2) {
        int g = lane >> 4, c = lane & 15;
        int mrow = wave * 16 + c;
        short8 a0 = *(const short8*)(&lds_x[mrow][g * 8]);
        short8 a1 = *(const short8*)(&lds_x[mrow][32 + g * 8]);

        float o[4][4];
#pragma unroll
        for (int r = 0; r < 4; ++r)
#pragma unroll
            for (int q = 0; q < 4; ++q) o[r][q] = 0.0f;

#pragma unroll
        for (int t = 0; t < 4; ++t) {
            short8 bf0 = *(const short8*)(w1f + ((size_t)((t * 2 + 0) * 64 + lane)) * 8);
            short8 bf1 = *(const short8*)(w1f + ((size_t)((t * 2 + 1) * 64 + lane)) * 8);
            f32x4 z = {0.f, 0.f, 0.f, 0.f};
            z = __builtin_amdgcn_mfma_f32_16x16x32_bf16(a0, bf0, z, 0, 0, 0);
            z = __builtin_amdgcn_mfma_f32_16x16x32_bf16(a1, bf1, z, 0, 0, 0);
            float  b1s = b1f[t * 64 + lane];
            float4 w2  = *(const float4*)(w2f + (size_t)(t * 64 + lane) * 4);
#pragma unroll
            for (int r = 0; r < 4; ++r) {
                float sp = softplusf(z[r] + b1s);
                o[r][0] = fmaf(sp, w2.x, o[r][0]);
                o[r][1] = fmaf(sp, w2.y, o[r][1]);
                o[r][2] = fmaf(sp, w2.z, o[r][2]);
                o[r][3] = fmaf(sp, w2.w, o[r][3]);
            }
        }
#pragma unroll
        for (int mask = 1; mask <= 8; mask <<= 1)
#pragma unroll
            for (int r = 0; r < 4; ++r)
#pragma unroll
                for (int q = 0; q < 4; ++q) o[r][q] += __shfl_xor(o[r][q], mask, 64);

        if (c == 0) {
#pragma unroll
            for (int r = 0; r < 4; ++r) {
                int pt = blockIdx.x * 32 + wave * 16 + g * 4 + r;
                float sig = o[r][0] + b2[0];
                float rr = sigmoidf(o[r][1] + b2[1]) * 1.002f - 0.001f;
                float gg = sigmoidf(o[r][2] + b2[2]) * 1.002f - 0.001f;
                float bb = sigmoidf(o[r][3] + b2[3]) * 1.002f - 0.001f;
                outRGBS[pt] = make_float4(rr, gg, bb, sig);
            }
        }
    }
}

// ========== coarse march -> cdf (shuffle scans) -> importance sample, fused ==========
#define CI_WAVES 4
__global__ __launch_bounds__(256) void cdf_imp(
    const float* __restrict__ depths_c, const float4* __restrict__ rgbs_c,
    const float* __restrict__ impu,
    float* __restrict__ depths_f, float* __restrict__ minmax)
{
    __shared__ float s_cdf[CI_WAVES][48];   // [0..45] cdf
    __shared__ float s_zm[CI_WAVES][48];    // [0..46] z_mid
    __shared__ float smn[CI_WAVES], smx[CI_WAVES];
    int wave = threadIdx.x >> 6, lane = threadIdx.x & 63;
    int ray = blockIdx.x * CI_WAVES + wave;

    float d = 0.f, sg = 0.f;
    if (lane < NC_) {
        d  = depths_c[ray * NC_ + lane];
        sg = rgbs_c[ray * NC_ + lane].w;
    }
    float dn = __shfl_down(d, 1, 64);
    float sn = __shfl_down(sg, 1, 64);
    bool iv = (lane < NC_ - 1);            // interval lanes 0..46

    float zm = 0.5f * (d + dn);
    float alpha = 0.f, f = 1.0f;
    if (iv) {
        float dens = softplusf(0.5f * (sg + sn) - 1.0f);
        alpha = 1.0f - __expf(-dens * (dn - d));
        f = 1.0f - alpha + 1e-10f;
    }
    float x = f;
#pragma unroll
    for (int s = 1; s < 64; s <<= 1) {
        float t = __shfl_up(x, s, 64);
        if (lane >= s) x *= t;
    }
    float excl = __shfl_up(x, 1, 64);
    if (lane == 0) excl = 1.0f;
    float w = alpha * excl;                // weights, lanes 0..46

    float wprev = __shfl_up(w, 1, 64);
    float wmax;                            // lanes 0..47
    if (lane == 0) wmax = w;
    else if (lane == NC_ - 1) wmax = wprev;
    else wmax = fmaxf(wprev, w);
    float wmaxn = __shfl_down(wmax, 1, 64);
    float wb = 0.5f * (wmax + wmaxn) + 0.01f;   // lanes 0..46

    float v = (lane >= 1 && lane <= 45) ? wb : 0.0f;
    float s = v;
#pragma unroll
    for (int mask = 1; mask <= 32; mask <<= 1) s += __shfl_xor(s, mask, 64);
    float pdf = v / s;
    float cum = pdf;
#pragma unroll
    for (int st = 1; st < 64; st <<= 1) {
        float t = __shfl_up(cum, st, 64);
        if (lane >= st) cum += t;
    }
    if (lane <= 45) s_cdf[wave][lane] = (lane == 0) ? 0.0f : cum;
    if (iv) s_zm[wave][lane] = zm;

    float d47 = __shfl(d, NC_ - 1, 64);
    if (lane == 0) { smn[wave] = d; smx[wave] = d47; }
    __syncthreads();
    if (threadIdx.x == 0) {
        float mn = smn[0], mx = smx[0];
#pragma unroll
        for (int i = 1; i < CI_WAVES; ++i) { mn = fminf(mn, smn[i]); mx = fmaxf(mx, smx[i]); }
        atomicMin((int*)minmax, __float_as_int(mn));
        atomicMax(((int*)minmax) + 1, __float_as_int(mx));
    }

    if (lane < NI_) {
        const float* cdf = s_cdf[wave];
        const float* zmp = s_zm[wave];
        float u = impu[ray * NI_ + lane];
        int lo = 0, hi = 46;
        while (lo < hi) { int mid = (lo + hi) >> 1; if (cdf[mid] > u) hi = mid; else lo = mid + 1; }
        int below = max(lo - 1, 0);
        int above = min(lo, 45);
        float c0 = cdf[below], c1 = cdf[above];
        float b0 = zmp[below], b1v = zmp[above];
        float den = c1 - c0; if (den < 1e-5f) den = 1.0f;
        depths_f[ray * NI_ + lane] = b0 + (u - c0) / den * (b1v - b0);
    }
}

// ---- merge + final march: ONE WAVE PER RAY, lane-parallel rank-merge + scan ----
#define FM_WAVES 4
__global__ __launch_bounds__(256) void final_march(
    const float* __restrict__ depths_c, const float4* __restrict__ rgbs_c,
    const float* __restrict__ depths_f, const float4* __restrict__ rgbs_f,
    const float* __restrict__ minmax, float* __restrict__ out)
{
    __shared__ float s_dc[FM_WAVES][NC_];
    __shared__ float s_df[FM_WAVES][NI_];
    __shared__ float s_md[FM_WAVES][96];
    __shared__ float s_ms[FM_WAVES][96];
    __shared__ float s_mr[FM_WAVES][96];
    __shared__ float s_mg[FM_WAVES][96];
    __shared__ float s_mb[FM_WAVES][96];

    int wave = threadIdx.x >> 6, lane = threadIdx.x & 63;
    int ray = blockIdx.x * FM_WAVES + wave;
    float* dcp = s_dc[wave];
    float* dfp = s_df[wave];
    float* mdp = s_md[wave];
    float* msp = s_ms[wave];
    float* mrp = s_mr[wave];
    float* mgp = s_mg[wave];
    float* mbp = s_mb[wave];

    float dcv = 0.f, dfv = 0.f;
    float4 c4 = make_float4(0, 0, 0, 0), f4 = make_float4(0, 0, 0, 0);
    if (lane < NC_) {
        dcv = depths_c[ray * NC_ + lane];
        dfv = depths_f[ray * NI_ + lane];
        dcp[lane] = dcv;
        dfp[lane] = dfv;
        c4 = rgbs_c[ray * NC_ + lane];
        f4 = rgbs_f[ray * NI_ + lane];
    }
    __syncthreads();

    if (lane < NC_) {
        int cntC = 0, rankF = 0, cntCle = 0;
#pragma unroll
        for (int j = 0; j < NC_; ++j) {
            float dfj = dfp[j];
            float dcj = dcp[j];
            cntC   += (dfj < dcv) ? 1 : 0;
            rankF  += ((dfj < dfv) || (dfj == dfv && j < lane)) ? 1 : 0;
            cntCle += (dcj <= dfv) ? 1 : 0;
        }
        int posC = lane + cntC;          // stable: coarse before equal fine
        int posF = rankF + cntCle;
        mdp[posC] = dcv; msp[posC] = c4.w; mrp[posC] = c4.x; mgp[posC] = c4.y; mbp[posC] = c4.z;
        mdp[posF] = dfv; msp[posF] = f4.w; mrp[posF] = f4.x; mgp[posF] = f4.y; mbp[posF] = f4.z;
    }
    __syncthreads();

    int k0 = 2 * lane;
    int i0 = min(k0, 95), i1 = min(k0 + 1, 95), i2 = min(k0 + 2, 95);
    float d0 = mdp[i0], d1 = mdp[i1], d2 = mdp[i2];
    float sg0 = msp[i0], sg1 = msp[i1], sg2 = msp[i2];
    float r0 = mrp[i0], r1 = mrp[i1], r2 = mrp[i2];
    float g0 = mgp[i0], g1 = mgp[i1], g2 = mgp[i2];
    float bb0 = mbp[i0], bb1 = mbp[i1], bb2 = mbp[i2];

    bool v0 = (k0 < 95), v1 = (k0 + 1 < 95);
    float a0 = 0.f, a1 = 0.f, f0 = 1.f, f1 = 1.f;
    if (v0) {
        float dens = softplusf(0.5f * (sg0 + sg1) - 1.0f);
        a0 = 1.0f - __expf(-dens * (d1 - d0));
        f0 = 1.0f - a0 + 1e-10f;
    }
    if (v1) {
        float dens = softplusf(0.5f * (sg1 + sg2) - 1.0f);
        a1 = 1.0f - __expf(-dens * (d2 - d1));
        f1 = 1.0f - a1 + 1e-10f;
    }

    float pl = f0 * f1;
    float x = pl;
#pragma unroll
    for (int d = 1; d < 64; d <<= 1) {
        float t = __shfl_up(x, d, 64);
        if (lane >= d) x *= t;
    }
    float excl = __shfl_up(x, 1, 64);
    if (lane == 0) excl = 1.0f;
    float w0 = a0 * excl;
    float w1 = a1 * excl * f0;

    float accR = w0 * 0.5f * (r0 + r1) + w1 * 0.5f * (r1 + r2);
    float accG = w0 * 0.5f * (g0 + g1) + w1 * 0.5f * (g1 + g2);
    float accB = w0 * 0.5f * (bb0 + bb1) + w1 * 0.5f * (bb1 + bb2);
    float accD = w0 * 0.5f * (d0 + d1) + w1 * 0.5f * (d1 + d2);
    float accW = w0 + w1;
#pragma unroll
    for (int mask = 1; mask <= 32; mask <<= 1) {
        accR += __shfl_xor(accR, mask, 64);
        accG += __shfl_xor(accG, mask, 64);
        accB += __shfl_xor(accB, mask, 64);
        accD += __shfl_xor(accD, mask, 64);
        accW += __shfl_xor(accW, mask, 64);
    }

    if (lane == 0) {
        float q = accD / accW;
        if (!isfinite(q)) q = 0.0f;
        q = fminf(fmaxf(q, minmax[0]), minmax[1]);
        out[ray * 3 + 0] = accR * 2.0f - 1.0f;
        out[ray * 3 + 1] = accG * 2.0f - 1.0f;
        out[ray * 3 + 2] = accB * 2.0f - 1.0f;
        out[3 * NRAY + ray] = q;
        out[4 * NRAY + ray] = accW;
    }
}

extern "C" void kernel_launch(void* const* d_in, const int* in_sizes, int n_in,
                              void* d_out, int out_size, void* d_ws, size_t ws_size,
                              hipStream_t stream)
{
    const float* planes_tex = (const float*)d_in[0];
    const float* planes_shp = (const float*)d_in[1];
    const float* origins    = (const float*)d_in[2];
    const float* raydirs    = (const float*)d_in[3];
    const float* W1 = (const float*)d_in[4];
    const float* b1 = (const float*)d_in[5];
    const float* W2 = (const float*)d_in[6];
    const float* b2 = (const float*)d_in[7];
    const float* noise = (const float*)d_in[8];
    const float* impu  = (const float*)d_in[9];
    float* out = (float*)d_out;

    char* ws = (char*)d_ws;
    __half*         planes_cl = (__half*)ws;                          // 50,331,648 B
    unsigned short* w1f       = (unsigned short*)(ws + 50331648);     // 8,192 B
    float*          w2f       = (float*)(ws + 50339840);              // 4,096 B
    float*          b1f       = (float*)(ws + 50343936);              // 1,024 B
    float*          minmax    = (float*)(ws + 50345216);              // 8 B (+pad)
    float*  depths_c = (float*)(ws + 50345472);                       // 1,572,864 B
    float*  depths_f = depths_c + NPTS;                               // 1,572,864 B
    float4* rgbs_c   = (float4*)(depths_f + NPTS);                    // 6,291,456 B
    float4* rgbs_f   = rgbs_c + NPTS;                                 // 6,291,456 B

    int fill_blocks = (NPTS + 255) / 256;                             // 1536
    setup_kernel<<<dim3(TR_BLOCKS + 1 + fill_blocks), dim3(256), 0, stream>>>(
        planes_tex, planes_shp, planes_cl, W1, b1, W2, w1f, w2f, b1f, minmax, noise, depths_c);

    fused_sample_mlp<<<dim3(NPTS / 32), dim3(256), 0, stream>>>(
        planes_cl, origins, raydirs, depths_c, w1f, w2f, b1f, b2, rgbs_c);

    cdf_imp<<<dim3(NRAY / CI_WAVES), dim3(256), 0, stream>>>(depths_c, rgbs_c, impu, depths_f, minmax);

    fused_sample_mlp<<<dim3(NPTS / 32), dim3(256), 0, stream>>>(
        planes_cl, origins, raydirs, depths_f, w1f, w2f, b1f, b2, rgbs_f);

    final_march<<<dim3(NRAY / FM_WAVES), dim3(256), 0, stream>>>(depths_c, rgbs_c, depths_f, rgbs_f, minmax, out);
}

// Round 9
// 321.211 us; speedup vs baseline: 1.1857x; 1.0501x over previous
//
#include <hip/hip_runtime.h>
#include <hip/hip_fp16.h>
#include <math.h>

#define NRAY 8192
#define NC_  48
#define NI_  48
#define CPL  32
#define HPL  256
#define HID  64
#define NPTS (NRAY * NC_)        // 393216 points per pass

typedef __attribute__((ext_vector_type(8))) short short8;   // 8 bf16
typedef __attribute__((ext_vector_type(4))) float f32x4;

__device__ __forceinline__ float softplusf(float x) {
    return fmaxf(x, 0.0f) + __logf(1.0f + __expf(-fabsf(x)));
}
__device__ __forceinline__ float sigmoidf(float x) {
    return 1.0f / (1.0f + __expf(-x));
}
__device__ __forceinline__ unsigned short f2bf(float f) {
    unsigned u = __float_as_uint(f);
    u += 0x7fffu + ((u >> 16) & 1u);
    return (unsigned short)(u >> 16);
}

// ================= setup mega-kernel =================
// blocks [0, 3072): transpose. block = (p in [0,12), y in [0,256)).
//   read fp32 (pp, c, y, x) coalesced -> LDS [x][c] fp16 -> uint4 stores to (pp, y, x, choff+c).
// block 3072: weight fragment prep + minmax init.
// blocks (3072, 3072+1536]: fill depths_c.
#define TR_BLOCKS 3072
__global__ __launch_bounds__(256) void setup_kernel(
    const float* __restrict__ tex, const float* __restrict__ shp,
    __half* __restrict__ planes_cl,
    const float* __restrict__ W1, const float* __restrict__ b1, const float* __restrict__ W2,
    unsigned short* __restrict__ w1f, float* __restrict__ w2f, float* __restrict__ b1f,
    float* __restrict__ minmax,
    const float* __restrict__ noise, float* __restrict__ depths)
{
    __shared__ __half t2[256][34];     // [x][c], padded: 17.4 KB, <=2-way banks
    int b = blockIdx.x;
    int tid = threadIdx.x;
    if (b < TR_BLOCKS) {
        int p = b >> 8;                // [0,12)
        int y = b & 255;
        const float* in = (p < 6) ? tex : shp;
        int pp    = (p < 6) ? p : p - 6;
        int choff = (p < 6) ? 0 : 32;
        const float* row = in + ((size_t)(pp * 32) * 256 + y) * 256;
#pragma unroll
        for (int c = 0; c < 32; ++c)
            t2[tid][c] = __float2half(row[(size_t)c * 65536 + tid]);
        __syncthreads();
        __half* outRow = planes_cl + ((size_t)(pp * 256 + y) * 256) * 64 + choff;
#pragma unroll
        for (int it = 0; it < 4; ++it) {
            int idx = it * 256 + tid;
            int x = idx >> 2, c8 = (idx & 3) * 8;
            *(uint4*)(outRow + (size_t)x * 64 + c8) = *(const uint4*)&t2[x][c8];
        }
    } else if (b == TR_BLOCKS) {
        int l = tid;
        if (l == 0) {
            ((int*)minmax)[0] = 0x7f800000;   // +inf
            ((int*)minmax)[1] = 0xff800000;   // -inf
        }
        if (l < 64) {
            int g = l >> 4, c = l & 15;
#pragma unroll
            for (int t = 0; t < 4; ++t) {
#pragma unroll
                for (int kb = 0; kb < 2; ++kb)
#pragma unroll
                    for (int j = 0; j < 8; ++j)
                        w1f[((t * 2 + kb) * 64 + l) * 8 + j] =
                            f2bf(W1[(kb * 32 + g * 8 + j) * HID + t * 16 + c]);
#pragma unroll
                for (int o = 0; o < 4; ++o) w2f[(t * 64 + l) * 4 + o] = W2[(t * 16 + c) * 4 + o];
                b1f[t * 64 + l] = b1[t * 16 + c];
            }
        }
    } else {
        int gid = (b - TR_BLOCKS - 1) * 256 + tid;
        if (gid < NPTS) {
            int s = gid % NC_;
            const float delta = (1.0f - 0.1f) / (NC_ - 1);
            depths[gid] = 0.1f + delta * (float)s + noise[gid] * delta;
        }
    }
}

// ================= fused plane-gather + MFMA MLP =================
// Block = 32 points. Phase A: 96 threads compute taps (1 thread per point-plane) -> LDS.
// Phase B: 8 threads/point x 8 channels gather (packed v_pk_fma_f16) -> LDS feature rows (bf16).
// Phase C: waves 0,1 run the MFMA MLP for 16 points each.
// __launch_bounds__(256,8): pin VGPR <= 64 so 8 waves/SIMD resident (latency hiding).
__global__ __launch_bounds__(256, 8) void fused_sample_mlp(
    const __half* __restrict__ planes,     // (6,256,256,64) interleaved fp16
    const float* __restrict__ origins, const float* __restrict__ dirs,
    const float* __restrict__ depths,      // [point]
    const unsigned short* __restrict__ w1f, const float* __restrict__ w2f,
    const float* __restrict__ b1f, const float* __restrict__ b2,
    float4* __restrict__ outRGBS)          // [point]
{
    __shared__ unsigned short lds_x[32][72];   // feature rows, stride 72 halves
    __shared__ int s_tap[32][12][2];           // (off, w-bits) pairs

    int tid = threadIdx.x;

    // ---------------- phase A: 1 thread per (point, plane) ----------------
    if (tid < 96) {
        int p  = tid & 31;
        int pp = tid >> 5;                 // plane 0..2
        int point = blockIdx.x * 32 + p;
        int ray = point / NC_;
        int bIdx = ray >> 12;

        float ox = origins[ray * 3 + 0], oy = origins[ray * 3 + 1], oz = origins[ray * 3 + 2];
        float dx = dirs[ray * 3 + 0], dy = dirs[ray * 3 + 1], dz = dirs[ray * 3 + 2];
        float invn = 1.0f / sqrtf(dx * dx + dy * dy + dz * dz);
        dx *= invn; dy *= invn; dz *= invn;
        float t = depths[point];
        float px = ox + t * dx, py = oy + t * dy, pz = oz + t * dz;

        // projections: p0:(x,y) p1:(x,z) p2:(z,x)
        float U = (pp == 2) ? pz : px;
        float V = (pp == 0) ? py : ((pp == 1) ? pz : px);
        const float inv3 = 1.0f / 3.0f;

        float gx = (U + 1.0f) * 128.0f - 0.5f;
        float gy = (V + 1.0f) * 128.0f - 0.5f;
        float fgx = floorf(gx), fgy = floorf(gy);
        int x0 = (int)fgx, y0 = (int)fgy;
        float fx = gx - fgx, fy = gy - fgy;
#pragma unroll
        for (int k = 0; k < 4; ++k) {
            int dxk = k & 1, dyk = k >> 1;
            int xi = x0 + dxk, yi = y0 + dyk;
            float w = (dxk ? fx : 1.0f - fx) * (dyk ? fy : 1.0f - fy);
            bool valid = (xi >= 0) && (xi < HPL) && (yi >= 0) && (yi < HPL);
            int xc = min(max(xi, 0), HPL - 1);
            int yc = min(max(yi, 0), HPL - 1);
            int p3 = bIdx * 3 + pp;
            s_tap[p][pp * 4 + k][0] = (((p3 * HPL) + yc) * HPL + xc) * 64;
            s_tap[p][pp * 4 + k][1] = __float_as_int(valid ? w * inv3 : 0.0f);
        }
    }
    __syncthreads();

    // ---------------- phase B: 8 threads/point, 8 channels each (packed fp16) ----------------
    {
        int p = tid >> 3, sub = tid & 7;
        int   off[12];
        float wv[12];
#pragma unroll
        for (int kk = 0; kk < 12; ++kk) {
            off[kk] = s_tap[p][kk][0];
            wv[kk]  = __int_as_float(s_tap[p][kk][1]);
        }
        __half2 acc2[4];
#pragma unroll
        for (int i = 0; i < 4; ++i) acc2[i] = __half2half2(__float2half(0.0f));
#pragma unroll
        for (int kk = 0; kk < 12; ++kk) {
            __half2 w2 = __half2half2(__float2half(wv[kk]));
            float4 v = *(const float4*)(planes + off[kk] + sub * 8);
            union { float4 f; __half2 h[4]; } u;
            u.f = v;
#pragma unroll
            for (int i = 0; i < 4; ++i) acc2[i] = __hfma2(u.h[i], w2, acc2[i]);
        }
        unsigned short u16[8];
#pragma unroll
        for (int i = 0; i < 4; ++i) {
            float2 f2 = __half22float2(acc2[i]);
            u16[2 * i]     = f2bf(f2.x);
            u16[2 * i + 1] = f2bf(f2.y);
        }
        *(uint4*)&lds_x[p][sub * 8] = *(uint4*)(u16);
    }
    __syncthreads();

    // ---------------- phase C: waves 0,1 -> MFMA MLP, 16 points each ----------------
    int lane = tid & 63, wave = tid >> 6;
    if (wave < 2) {
        int g = lane >> 4, c = lane & 15;
        int mrow = wave * 16 + c;
        short8 a0 = *(const short8*)(&lds_x[mrow][g * 8]);
        short8 a1 = *(const short8*)(&lds_x[mrow][32 + g * 8]);

        float o[4][4];
#pragma unroll
        for (int r = 0; r < 4; ++r)
#pragma unroll
            for (int q = 0; q < 4; ++q) o[r][q] = 0.0f;

#pragma unroll
        for (int t = 0; t < 4; ++t) {
            short8 bf0 = *(const short8*)(w1f + ((size_t)((t * 2 + 0) * 64 + lane)) * 8);
            short8 bf1 = *(const short8*)(w1f + ((size_t)((t * 2 + 1) * 64 + lane)) * 8);
            f32x4 z = {0.f, 0.f, 0.f, 0.f};
            z = __builtin_amdgcn_mfma_f32_16x16x32_bf16(a0, bf0, z, 0, 0, 0);
            z = __builtin_amdgcn_mfma_f32_16x16x32_bf16(a1, bf1, z, 0, 0, 0);
            float  b1s = b1f[t * 64 + lane];
            float4 w2  = *(const float4*)(w2f + (size_t)(t * 64 + lane) * 4);
#pragma unroll
            for (int r = 0; r < 4; ++r) {
                float sp = softplusf(z[r] + b1s);
                o[r][0] = fmaf(sp, w2.x, o[r][0]);
                o[r][1] = fmaf(sp, w2.y, o[r][1]);
                o[r][2] = fmaf(sp, w2.z, o[r][2]);
                o[r][3] = fmaf(sp, w2.w, o[r][3]);
            }
        }
#pragma unroll
        for (int mask = 1; mask <= 8; mask <<= 1)
#pragma unroll
            for (int r = 0; r < 4; ++r)
#pragma unroll
                for (int q = 0; q < 4; ++q) o[r][q] += __shfl_xor(o[r][q], mask, 64);

        if (c == 0) {
#pragma unroll
            for (int r = 0; r < 4; ++r) {
                int pt = blockIdx.x * 32 + wave * 16 + g * 4 + r;
                float sig = o[r][0] + b2[0];
                float rr = sigmoidf(o[r][1] + b2[1]) * 1.002f - 0.001f;
                float gg = sigmoidf(o[r][2] + b2[2]) * 1.002f - 0.001f;
                float bb = sigmoidf(o[r][3] + b2[3]) * 1.002f - 0.001f;
                outRGBS[pt] = make_float4(rr, gg, bb, sig);
            }
        }
    }
}

// ========== coarse march -> cdf (shuffle scans) -> importance sample, fused ==========
#define CI_WAVES 4
__global__ __launch_bounds__(256) void cdf_imp(
    const float* __restrict__ depths_c, const float4* __restrict__ rgbs_c,
    const float* __restrict__ impu,
    float* __restrict__ depths_f, float* __restrict__ minmax)
{
    __shared__ float s_cdf[CI_WAVES][48];   // [0..45] cdf
    __shared__ float s_zm[CI_WAVES][48];    // [0..46] z_mid
    __shared__ float smn[CI_WAVES], smx[CI_WAVES];
    int wave = threadIdx.x >> 6, lane = threadIdx.x & 63;
    int ray = blockIdx.x * CI_WAVES + wave;

    float d = 0.f, sg = 0.f;
    if (lane < NC_) {
        d  = depths_c[ray * NC_ + lane];
        sg = rgbs_c[ray * NC_ + lane].w;
    }
    float dn = __shfl_down(d, 1, 64);
    float sn = __shfl_down(sg, 1, 64);
    bool iv = (lane < NC_ - 1);            // interval lanes 0..46

    float zm = 0.5f * (d + dn);
    float alpha = 0.f, f = 1.0f;
    if (iv) {
        float dens = softplusf(0.5f * (sg + sn) - 1.0f);
        alpha = 1.0f - __expf(-dens * (dn - d));
        f = 1.0f - alpha + 1e-10f;
    }
    float x = f;
#pragma unroll
    for (int s = 1; s < 64; s <<= 1) {
        float t = __shfl_up(x, s, 64);
        if (lane >= s) x *= t;
    }
    float excl = __shfl_up(x, 1, 64);
    if (lane == 0) excl = 1.0f;
    float w = alpha * excl;                // weights, lanes 0..46

    float wprev = __shfl_up(w, 1, 64);
    float wmax;                            // lanes 0..47
    if (lane == 0) wmax = w;
    else if (lane == NC_ - 1) wmax = wprev;
    else wmax = fmaxf(wprev, w);
    float wmaxn = __shfl_down(wmax, 1, 64);
    float wb = 0.5f * (wmax + wmaxn) + 0.01f;   // lanes 0..46

    float v = (lane >= 1 && lane <= 45) ? wb : 0.0f;
    float s = v;
#pragma unroll
    for (int mask = 1; mask <= 32; mask <<= 1) s += __shfl_xor(s, mask, 64);
    float pdf = v / s;
    float cum = pdf;
#pragma unroll
    for (int st = 1; st < 64; st <<= 1) {
        float t = __shfl_up(cum, st, 64);
        if (lane >= st) cum += t;
    }
    if (lane <= 45) s_cdf[wave][lane] = (lane == 0) ? 0.0f : cum;
    if (iv) s_zm[wave][lane] = zm;

    float d47 = __shfl(d, NC_ - 1, 64);
    if (lane == 0) { smn[wave] = d; smx[wave] = d47; }
    __syncthreads();
    if (threadIdx.x == 0) {
        float mn = smn[0], mx = smx[0];
#pragma unroll
        for (int i = 1; i < CI_WAVES; ++i) { mn = fminf(mn, smn[i]); mx = fmaxf(mx, smx[i]); }
        atomicMin((int*)minmax, __float_as_int(mn));
        atomicMax(((int*)minmax) + 1, __float_as_int(mx));
    }

    if (lane < NI_) {
        const float* cdf = s_cdf[wave];
        const float* zmp = s_zm[wave];
        float u = impu[ray * NI_ + lane];
        int lo = 0, hi = 46;
        while (lo < hi) { int mid = (lo + hi) >> 1; if (cdf[mid] > u) hi = mid; else lo = mid + 1; }
        int below = max(lo - 1, 0);
        int above = min(lo, 45);
        float c0 = cdf[below], c1 = cdf[above];
        float b0 = zmp[below], b1v = zmp[above];
        float den = c1 - c0; if (den < 1e-5f) den = 1.0f;
        depths_f[ray * NI_ + lane] = b0 + (u - c0) / den * (b1v - b0);
    }
}

// ---- merge + final march: ONE WAVE PER RAY, lane-parallel rank-merge + scan ----
#define FM_WAVES 4
__global__ __launch_bounds__(256) void final_march(
    const float* __restrict__ depths_c, const float4* __restrict__ rgbs_c,
    const float* __restrict__ depths_f, const float4* __restrict__ rgbs_f,
    const float* __restrict__ minmax, float* __restrict__ out)
{
    __shared__ float s_dc[FM_WAVES][NC_];
    __shared__ float s_df[FM_WAVES][NI_];
    __shared__ float s_md[FM_WAVES][96];
    __shared__ float s_ms[FM_WAVES][96];
    __shared__ float s_mr[FM_WAVES][96];
    __shared__ float s_mg[FM_WAVES][96];
    __shared__ float s_mb[FM_WAVES][96];

    int wave = threadIdx.x >> 6, lane = threadIdx.x & 63;
    int ray = blockIdx.x * FM_WAVES + wave;
    float* dcp = s_dc[wave];
    float* dfp = s_df[wave];
    float* mdp = s_md[wave];
    float* msp = s_ms[wave];
    float* mrp = s_mr[wave];
    float* mgp = s_mg[wave];
    float* mbp = s_mb[wave];

    float dcv = 0.f, dfv = 0.f;
    float4 c4 = make_float4(0, 0, 0, 0), f4 = make_float4(0, 0, 0, 0);
    if (lane < NC_) {
        dcv = depths_c[ray * NC_ + lane];
        dfv = depths_f[ray * NI_ + lane];
        dcp[lane] = dcv;
        dfp[lane] = dfv;
        c4 = rgbs_c[ray * NC_ + lane];
        f4 = rgbs_f[ray * NI_ + lane];
    }
    __syncthreads();

    if (lane < NC_) {
        int cntC = 0, rankF = 0, cntCle = 0;
#pragma unroll
        for (int j = 0; j < NC_; ++j) {
            float dfj = dfp[j];
            float dcj = dcp[j];
            cntC   += (dfj < dcv) ? 1 : 0;
            rankF  += ((dfj < dfv) || (dfj == dfv && j < lane)) ? 1 : 0;
            cntCle += (dcj <= dfv) ? 1 : 0;
        }
        int posC = lane + cntC;          // stable: coarse before equal fine
        int posF = rankF + cntCle;
        mdp[posC] = dcv; msp[posC] = c4.w; mrp[posC] = c4.x; mgp[posC] = c4.y; mbp[posC] = c4.z;
        mdp[posF] = dfv; msp[posF] = f4.w; mrp[posF] = f4.x; mgp[posF] = f4.y; mbp[posF] = f4.z;
    }
    __syncthreads();

    int k0 = 2 * lane;
    int i0 = min(k0, 95), i1 = min(k0 + 1, 95), i2 = min(k0 + 2, 95);
    float d0 = mdp[i0], d1 = mdp[i1], d2 = mdp[i2];
    float sg0 = msp[i0], sg1 = msp[i1], sg2 = msp[i2];
    float r0 = mrp[i0], r1 = mrp[i1], r2 = mrp[i2];
    float g0 = mgp[i0], g1 = mgp[i1], g2 = mgp[i2];
    float bb0 = mbp[i0], bb1 = mbp[i1], bb2 = mbp[i2];

    bool v0 = (k0 < 95), v1 = (k0 + 1 < 95);
    float a0 = 0.f, a1 = 0.f, f0 = 1.f, f1 = 1.f;
    if (v0) {
        float dens = softplusf(0.5f * (sg0 + sg1) - 1.0f);
        a0 = 1.0f - __expf(-dens * (d1 - d0));
        f0 = 1.0f - a0 + 1e-10f;
    }
    if (v1) {
        float dens = softplusf(0.5f * (sg1 + sg2) - 1.0f);
        a1 = 1.0f - __expf(-dens * (d2 - d1));
        f1 = 1.0f - a1 + 1e-10f;
    }

    float pl = f0 * f1;
    float x = pl;
#pragma unroll
    for (int d = 1; d < 64; d <<= 1) {
        float t = __shfl_up(x, d, 64);
        if (lane >= d) x *= t;
    }
    float excl = __shfl_up(x, 1, 64);
    if (lane == 0) excl = 1.0f;
    float w0 = a0 * excl;
    float w1 = a1 * excl * f0;

    float accR = w0 * 0.5f * (r0 + r1) + w1 * 0.5f * (r1 + r2);
    float accG = w0 * 0.5f * (g0 + g1) + w1 * 0.5f * (g1 + g2);
    float accB = w0 * 0.5f * (bb0 + bb1) + w1 * 0.5f * (bb1 + bb2);
    float accD = w0 * 0.5f * (d0 + d1) + w1 * 0.5f * (d1 + d2);
    float accW = w0 + w1;
#pragma unroll
    for (int mask = 1; mask <= 32; mask <<= 1) {
        accR += __shfl_xor(accR, mask, 64);
        accG += __shfl_xor(accG, mask, 64);
        accB += __shfl_xor(accB, mask, 64);
        accD += __shfl_xor(accD, mask, 64);
        accW += __shfl_xor(accW, mask, 64);
    }

    if (lane == 0) {
        float q = accD / accW;
        if (!isfinite(q)) q = 0.0f;
        q = fminf(fmaxf(q, minmax[0]), minmax[1]);
        out[ray * 3 + 0] = accR * 2.0f - 1.0f;
        out[ray * 3 + 1] = accG * 2.0f - 1.0f;
        out[ray * 3 + 2] = accB * 2.0f - 1.0f;
        out[3 * NRAY + ray] = q;
        out[4 * NRAY + ray] = accW;
    }
}

extern "C" void kernel_launch(void* const* d_in, const int* in_sizes, int n_in,
                              void* d_out, int out_size, void* d_ws, size_t ws_size,
                              hipStream_t stream)
{
    const float* planes_tex = (const float*)d_in[0];
    const float* planes_shp = (const float*)d_in[1];
    const float* origins    = (const float*)d_in[2];
    const float* raydirs    = (const float*)d_in[3];
    const float* W1 = (const float*)d_in[4];
    const float* b1 = (const float*)d_in[5];
    const float* W2 = (const float*)d_in[6];
    const float* b2 = (const float*)d_in[7];
    const float* noise = (const float*)d_in[8];
    const float* impu  = (const float*)d_in[9];
    float* out = (float*)d_out;

    char* ws = (char*)d_ws;
    __half*         planes_cl = (__half*)ws;                          // 50,331,648 B
    unsigned short* w1f       = (unsigned short*)(ws + 50331648);     // 8,192 B
    float*          w2f       = (float*)(ws + 50339840);              // 4,096 B
    float*          b1f       = (float*)(ws + 50343936);              // 1,024 B
    float*          minmax    = (float*)(ws + 50345216);              // 8 B (+pad)
    float*  depths_c = (float*)(ws + 50345472);                       // 1,572,864 B
    float*  depths_f = depths_c + NPTS;                               // 1,572,864 B
    float4* rgbs_c   = (float4*)(depths_f + NPTS);                    // 6,291,456 B
    float4* rgbs_f   = rgbs_c + NPTS;                                 // 6,291,456 B

    int fill_blocks = (NPTS + 255) / 256;                             // 1536
    setup_kernel<<<dim3(TR_BLOCKS + 1 + fill_blocks), dim3(256), 0, stream>>>(
        planes_tex, planes_shp, planes_cl, W1, b1, W2, w1f, w2f, b1f, minmax, noise, depths_c);

    fused_sample_mlp<<<dim3(NPTS / 32), dim3(256), 0, stream>>>(
        planes_cl, origins, raydirs, depths_c, w1f, w2f, b1f, b2, rgbs_c);

    cdf_imp<<<dim3(NRAY / CI_WAVES), dim3(256), 0, stream>>>(depths_c, rgbs_c, impu, depths_f, minmax);

    fused_sample_mlp<<<dim3(NPTS / 32), dim3(256), 0, stream>>>(
        planes_cl, origins, raydirs, depths_f, w1f, w2f, b1f, b2, rgbs_f);

    final_march<<<dim3(NRAY / FM_WAVES), dim3(256), 0, stream>>>(depths_c, rgbs_c, depths_f, rgbs_f, minmax, out);
}

// Round 10
// 282.701 us; speedup vs baseline: 1.3472x; 1.1362x over previous
//
#include <hip/hip_runtime.h>
#include <hip/hip_fp16.h>
#include <math.h>

#define NRAY 8192
#define NC_  48
#define NI_  48
#define HPL  256
#define HID  64
#define NPTS (NRAY * NC_)        // 393216 points per pass

typedef __attribute__((ext_vector_type(8))) short short8;   // 8 bf16
typedef __attribute__((ext_vector_type(4))) float f32x4;

__device__ __forceinline__ float softplusf(float x) {
    return fmaxf(x, 0.0f) + __logf(1.0f + __expf(-fabsf(x)));
}
__device__ __forceinline__ float sigmoidf(float x) {
    return 1.0f / (1.0f + __expf(-x));
}
__device__ __forceinline__ unsigned short f2bf(float f) {
    unsigned u = __float_as_uint(f);
    u += 0x7fffu + ((u >> 16) & 1u);
    return (unsigned short)(u >> 16);
}

// ================= setup mega-kernel =================
// blocks [0, 3072): transpose (p in [0,12), y in [0,256)) -> fp16 channel-last interleaved.
// block 3072: weight fragment prep.
// blocks 3073..3088: minmax partials from noise (no atomics).
#define TR_BLOCKS 3072
__global__ __launch_bounds__(256) void setup_kernel(
    const float* __restrict__ tex, const float* __restrict__ shp,
    __half* __restrict__ planes_cl,
    const float* __restrict__ W1, const float* __restrict__ b1, const float* __restrict__ W2,
    unsigned short* __restrict__ w1f, float* __restrict__ w2f, float* __restrict__ b1f,
    float* __restrict__ part_mn, float* __restrict__ part_mx,
    const float* __restrict__ noise)
{
    __shared__ __half t2[256][34];     // [x][c], padded
    __shared__ float smn[4], smx[4];
    int b = blockIdx.x;
    int tid = threadIdx.x;
    if (b < TR_BLOCKS) {
        int p = b >> 8;                // [0,12)
        int y = b & 255;
        const float* in = (p < 6) ? tex : shp;
        int pp    = (p < 6) ? p : p - 6;
        int choff = (p < 6) ? 0 : 32;
        const float* row = in + ((size_t)(pp * 32) * 256 + y) * 256;
#pragma unroll
        for (int c = 0; c < 32; ++c)
            t2[tid][c] = __float2half(row[(size_t)c * 65536 + tid]);
        __syncthreads();
        __half* outRow = planes_cl + ((size_t)(pp * 256 + y) * 256) * 64 + choff;
#pragma unroll
        for (int it = 0; it < 4; ++it) {
            int idx = it * 256 + tid;
            int x = idx >> 2, c8 = (idx & 3) * 8;
            *(uint4*)(outRow + (size_t)x * 64 + c8) = *(const uint4*)&t2[x][c8];
        }
    } else if (b == TR_BLOCKS) {
        int l = tid;
        if (l < 64) {
            int g = l >> 4, c = l & 15;
#pragma unroll
            for (int t = 0; t < 4; ++t) {
#pragma unroll
                for (int kb = 0; kb < 2; ++kb)
#pragma unroll
                    for (int j = 0; j < 8; ++j)
                        w1f[((t * 2 + kb) * 64 + l) * 8 + j] =
                            f2bf(W1[(kb * 32 + g * 8 + j) * HID + t * 16 + c]);
#pragma unroll
                for (int o = 0; o < 4; ++o) w2f[(t * 64 + l) * 4 + o] = W2[(t * 16 + c) * 4 + o];
                b1f[t * 64 + l] = b1[t * 16 + c];
            }
        }
    } else {
        // minmax partials: depths min = 0.1 + delta*min(noise[r,0]); max = 1.0 + delta*max(noise[r,47])
        int bl = b - TR_BLOCKS - 1;            // [0,16)
        int gtid = bl * 256 + tid;             // [0,4096)
        float mn = INFINITY, mx = -INFINITY;
        for (int r = gtid; r < NRAY; r += 4096) {
            mn = fminf(mn, noise[r * NC_]);
            mx = fmaxf(mx, noise[r * NC_ + NC_ - 1]);
        }
#pragma unroll
        for (int mask = 1; mask <= 32; mask <<= 1) {
            mn = fminf(mn, __shfl_xor(mn, mask, 64));
            mx = fmaxf(mx, __shfl_xor(mx, mask, 64));
        }
        int wv = tid >> 6;
        if ((tid & 63) == 0) { smn[wv] = mn; smx[wv] = mx; }
        __syncthreads();
        if (tid == 0) {
#pragma unroll
            for (int i = 1; i < 4; ++i) { mn = fminf(mn, smn[i]); mx = fmaxf(mx, smx[i]); }
            const float delta = (1.0f - 0.1f) / (NC_ - 1);
            part_mn[bl] = 0.1f + mn * delta;                    // s = 0 term
            part_mx[bl] = 0.1f + delta * 47.0f + mx * delta;    // s = 47 term
        }
    }
}

// ================= fused plane-gather + MFMA MLP (coarse & fine) =================
// Block = 32 points.
// FINE prologue: waves 0-1 recompute the cdf/z_mid of the <=2 rays this block spans (shuffle scans).
// Phase A: 96 threads (1 per point-plane): depth (inline noise-depth or cdf-inverse) + taps -> LDS.
// Phase B: 8 threads/point x 8 channels gather (packed fp16 fma) -> LDS feature rows (bf16).
// Phase C: waves 0,1 run the MFMA MLP for 16 points each.
template<bool FINE>
__global__ __launch_bounds__(256, 8) void fused_sample_mlp(
    const __half* __restrict__ planes,     // (6,256,256,64) interleaved fp16
    const float* __restrict__ origins, const float* __restrict__ dirs,
    const float* __restrict__ noise,       // coarse only
    const float* __restrict__ impu,        // fine only
    const float* __restrict__ depths_c,    // fine only (read, per-ray rows)
    const float4* __restrict__ rgbs_c_in,  // fine only (read sigma)
    float* __restrict__ depths_out,        // write: depths_c (coarse) / depths_f (fine)
    const unsigned short* __restrict__ w1f, const float* __restrict__ w2f,
    const float* __restrict__ b1f, const float* __restrict__ b2,
    float4* __restrict__ outRGBS)          // [point]
{
    __shared__ unsigned short lds_x[32][72];   // feature rows, stride 72 halves
    __shared__ int s_tap[32][12][2];           // (off, w-bits) pairs
    __shared__ float s_cdf[2][48];             // FINE: [0..45] cdf per local ray
    __shared__ float s_zm[2][48];              // FINE: [0..46] z_mid per local ray

    int tid = threadIdx.x;
    int r0 = (blockIdx.x * 32) / NC_;

    if constexpr (FINE) {
        int wv = tid >> 6, lane = tid & 63;
        int r1 = (blockIdx.x * 32 + 31) / NC_;
        if (wv <= r1 - r0) {                   // wave 0 always; wave 1 iff block spans 2 rays
            int ray = r0 + wv;
            float d = 0.f, sg = 0.f;
            if (lane < NC_) {
                d  = depths_c[ray * NC_ + lane];
                sg = rgbs_c_in[ray * NC_ + lane].w;
            }
            float dn = __shfl_down(d, 1, 64);
            float sn = __shfl_down(sg, 1, 64);
            bool iv = (lane < NC_ - 1);
            float zm = 0.5f * (d + dn);
            float alpha = 0.f, f = 1.0f;
            if (iv) {
                float dens = softplusf(0.5f * (sg + sn) - 1.0f);
                alpha = 1.0f - __expf(-dens * (dn - d));
                f = 1.0f - alpha + 1e-10f;
            }
            float x = f;
#pragma unroll
            for (int s = 1; s < 64; s <<= 1) {
                float t = __shfl_up(x, s, 64);
                if (lane >= s) x *= t;
            }
            float excl = __shfl_up(x, 1, 64);
            if (lane == 0) excl = 1.0f;
            float w = alpha * excl;
            float wprev = __shfl_up(w, 1, 64);
            float wmax;
            if (lane == 0) wmax = w;
            else if (lane == NC_ - 1) wmax = wprev;
            else wmax = fmaxf(wprev, w);
            float wmaxn = __shfl_down(wmax, 1, 64);
            float wb = 0.5f * (wmax + wmaxn) + 0.01f;
            float v = (lane >= 1 && lane <= 45) ? wb : 0.0f;
            float ssum = v;
#pragma unroll
            for (int mask = 1; mask <= 32; mask <<= 1) ssum += __shfl_xor(ssum, mask, 64);
            float pdf = v / ssum;
            float cum = pdf;
#pragma unroll
            for (int st = 1; st < 64; st <<= 1) {
                float t = __shfl_up(cum, st, 64);
                if (lane >= st) cum += t;
            }
            if (lane <= 45) s_cdf[wv][lane] = (lane == 0) ? 0.0f : cum;
            if (iv) s_zm[wv][lane] = zm;
        }
        __syncthreads();
    }

    // ---------------- phase A: 1 thread per (point, plane) ----------------
    if (tid < 96) {
        int p  = tid & 31;
        int pp = tid >> 5;                 // plane 0..2
        int point = blockIdx.x * 32 + p;
        int ray = point / NC_;
        int bIdx = ray >> 12;

        float t;
        if constexpr (!FINE) {
            int s = point - ray * NC_;
            const float delta = (1.0f - 0.1f) / (NC_ - 1);
            t = 0.1f + delta * (float)s + noise[point] * delta;
        } else {
            int ridx = ray - r0;
            float u = impu[point];
            const float* cdf = s_cdf[ridx];
            const float* zmp = s_zm[ridx];
            int lo = 0, hi = 46;
            while (lo < hi) { int mid = (lo + hi) >> 1; if (cdf[mid] > u) hi = mid; else lo = mid + 1; }
            int below = max(lo - 1, 0);
            int above = min(lo, 45);
            float c0 = cdf[below], c1 = cdf[above];
            float b0 = zmp[below], b1v = zmp[above];
            float den = c1 - c0; if (den < 1e-5f) den = 1.0f;
            t = b0 + (u - c0) / den * (b1v - b0);
        }
        if (pp == 0) depths_out[point] = t;

        float ox = origins[ray * 3 + 0], oy = origins[ray * 3 + 1], oz = origins[ray * 3 + 2];
        float dx = dirs[ray * 3 + 0], dy = dirs[ray * 3 + 1], dz = dirs[ray * 3 + 2];
        float invn = 1.0f / sqrtf(dx * dx + dy * dy + dz * dz);
        dx *= invn; dy *= invn; dz *= invn;
        float px = ox + t * dx, py = oy + t * dy, pz = oz + t * dz;

        // projections: p0:(x,y) p1:(x,z) p2:(z,x)
        float U = (pp == 2) ? pz : px;
        float V = (pp == 0) ? py : ((pp == 1) ? pz : px);
        const float inv3 = 1.0f / 3.0f;

        float gx = (U + 1.0f) * 128.0f - 0.5f;
        float gy = (V + 1.0f) * 128.0f - 0.5f;
        float fgx = floorf(gx), fgy = floorf(gy);
        int x0 = (int)fgx, y0 = (int)fgy;
        float fx = gx - fgx, fy = gy - fgy;
#pragma unroll
        for (int k = 0; k < 4; ++k) {
            int dxk = k & 1, dyk = k >> 1;
            int xi = x0 + dxk, yi = y0 + dyk;
            float w = (dxk ? fx : 1.0f - fx) * (dyk ? fy : 1.0f - fy);
            bool valid = (xi >= 0) && (xi < HPL) && (yi >= 0) && (yi < HPL);
            int xc = min(max(xi, 0), HPL - 1);
            int yc = min(max(yi, 0), HPL - 1);
            int p3 = bIdx * 3 + pp;
            s_tap[p][pp * 4 + k][0] = (((p3 * HPL) + yc) * HPL + xc) * 64;
            s_tap[p][pp * 4 + k][1] = __float_as_int(valid ? w * inv3 : 0.0f);
        }
    }
    __syncthreads();

    // ---------------- phase B: 8 threads/point, 8 channels each (packed fp16) ----------------
    {
        int p = tid >> 3, sub = tid & 7;
        int   off[12];
        float wv[12];
#pragma unroll
        for (int kk = 0; kk < 12; ++kk) {
            off[kk] = s_tap[p][kk][0];
            wv[kk]  = __int_as_float(s_tap[p][kk][1]);
        }
        __half2 acc2[4];
#pragma unroll
        for (int i = 0; i < 4; ++i) acc2[i] = __half2half2(__float2half(0.0f));
#pragma unroll
        for (int kk = 0; kk < 12; ++kk) {
            __half2 w2 = __half2half2(__float2half(wv[kk]));
            float4 v = *(const float4*)(planes + off[kk] + sub * 8);
            union { float4 f; __half2 h[4]; } u;
            u.f = v;
#pragma unroll
            for (int i = 0; i < 4; ++i) acc2[i] = __hfma2(u.h[i], w2, acc2[i]);
        }
        unsigned short u16[8];
#pragma unroll
        for (int i = 0; i < 4; ++i) {
            float2 f2 = __half22float2(acc2[i]);
            u16[2 * i]     = f2bf(f2.x);
            u16[2 * i + 1] = f2bf(f2.y);
        }
        *(uint4*)&lds_x[p][sub * 8] = *(uint4*)(u16);
    }
    __syncthreads();

    // ---------------- phase C: waves 0,1 -> MFMA MLP, 16 points each ----------------
    int lane = tid & 63, wave = tid >> 6;
    if (wave < 2) {
        int g = lane >> 4, c = lane & 15;
        int mrow = wave * 16 + c;
        short8 a0 = *(const short8*)(&lds_x[mrow][g * 8]);
        short8 a1 = *(const short8*)(&lds_x[mrow][32 + g * 8]);

        float o[4][4];
#pragma unroll
        for (int r = 0; r < 4; ++r)
#pragma unroll
            for (int q = 0; q < 4; ++q) o[r][q] = 0.0f;

#pragma unroll
        for (int t = 0; t < 4; ++t) {
            short8 bf0 = *(const short8*)(w1f + ((size_t)((t * 2 + 0) * 64 + lane)) * 8);
            short8 bf1 = *(const short8*)(w1f + ((size_t)((t * 2 + 1) * 64 + lane)) * 8);
            f32x4 z = {0.f, 0.f, 0.f, 0.f};
            z = __builtin_amdgcn_mfma_f32_16x16x32_bf16(a0, bf0, z, 0, 0, 0);
            z = __builtin_amdgcn_mfma_f32_16x16x32_bf16(a1, bf1, z, 0, 0, 0);
            float  b1s = b1f[t * 64 + lane];
            float4 w2  = *(const float4*)(w2f + (size_t)(t * 64 + lane) * 4);
#pragma unroll
            for (int r = 0; r < 4; ++r) {
                float sp = softplusf(z[r] + b1s);
                o[r][0] = fmaf(sp, w2.x, o[r][0]);
                o[r][1] = fmaf(sp, w2.y, o[r][1]);
                o[r][2] = fmaf(sp, w2.z, o[r][2]);
                o[r][3] = fmaf(sp, w2.w, o[r][3]);
            }
        }
#pragma unroll
        for (int mask = 1; mask <= 8; mask <<= 1)
#pragma unroll
            for (int r = 0; r < 4; ++r)
#pragma unroll
                for (int q = 0; q < 4; ++q) o[r][q] += __shfl_xor(o[r][q], mask, 64);

        if (c == 0) {
#pragma unroll
            for (int r = 0; r < 4; ++r) {
                int pt = blockIdx.x * 32 + wave * 16 + g * 4 + r;
                float sig = o[r][0] + b2[0];
                float rr = sigmoidf(o[r][1] + b2[1]) * 1.002f - 0.001f;
                float gg = sigmoidf(o[r][2] + b2[2]) * 1.002f - 0.001f;
                float bb = sigmoidf(o[r][3] + b2[3]) * 1.002f - 0.001f;
                outRGBS[pt] = make_float4(rr, gg, bb, sig);
            }
        }
    }
}

// ---- merge + final march: ONE WAVE PER RAY, lane-parallel rank-merge + scan ----
#define FM_WAVES 4
__global__ __launch_bounds__(256) void final_march(
    const float* __restrict__ depths_c, const float4* __restrict__ rgbs_c,
    const float* __restrict__ depths_f, const float4* __restrict__ rgbs_f,
    const float* __restrict__ part_mn, const float* __restrict__ part_mx,
    float* __restrict__ out)
{
    __shared__ float s_dc[FM_WAVES][NC_];
    __shared__ float s_df[FM_WAVES][NI_];
    __shared__ float s_md[FM_WAVES][96];
    __shared__ float s_ms[FM_WAVES][96];
    __shared__ float s_mr[FM_WAVES][96];
    __shared__ float s_mg[FM_WAVES][96];
    __shared__ float s_mb[FM_WAVES][96];

    int wave = threadIdx.x >> 6, lane = threadIdx.x & 63;
    int ray = blockIdx.x * FM_WAVES + wave;
    float* dcp = s_dc[wave];
    float* dfp = s_df[wave];
    float* mdp = s_md[wave];
    float* msp = s_ms[wave];
    float* mrp = s_mr[wave];
    float* mgp = s_mg[wave];
    float* mbp = s_mb[wave];

    float dcv = 0.f, dfv = 0.f;
    float4 c4 = make_float4(0, 0, 0, 0), f4 = make_float4(0, 0, 0, 0);
    if (lane < NC_) {
        dcv = depths_c[ray * NC_ + lane];
        dfv = depths_f[ray * NI_ + lane];
        dcp[lane] = dcv;
        dfp[lane] = dfv;
        c4 = rgbs_c[ray * NC_ + lane];
        f4 = rgbs_f[ray * NI_ + lane];
    }
    __syncthreads();

    if (lane < NC_) {
        int cntC = 0, rankF = 0, cntCle = 0;
#pragma unroll
        for (int j = 0; j < NC_; ++j) {
            float dfj = dfp[j];
            float dcj = dcp[j];
            cntC   += (dfj < dcv) ? 1 : 0;
            rankF  += ((dfj < dfv) || (dfj == dfv && j < lane)) ? 1 : 0;
            cntCle += (dcj <= dfv) ? 1 : 0;
        }
        int posC = lane + cntC;          // stable: coarse before equal fine
        int posF = rankF + cntCle;
        mdp[posC] = dcv; msp[posC] = c4.w; mrp[posC] = c4.x; mgp[posC] = c4.y; mbp[posC] = c4.z;
        mdp[posF] = dfv; msp[posF] = f4.w; mrp[posF] = f4.x; mgp[posF] = f4.y; mbp[posF] = f4.z;
    }
    __syncthreads();

    int k0 = 2 * lane;
    int i0 = min(k0, 95), i1 = min(k0 + 1, 95), i2 = min(k0 + 2, 95);
    float d0 = mdp[i0], d1 = mdp[i1], d2 = mdp[i2];
    float sg0 = msp[i0], sg1 = msp[i1], sg2 = msp[i2];
    float r0 = mrp[i0], r1 = mrp[i1], r2 = mrp[i2];
    float g0 = mgp[i0], g1 = mgp[i1], g2 = mgp[i2];
    float bb0 = mbp[i0], bb1 = mbp[i1], bb2 = mbp[i2];

    bool v0 = (k0 < 95), v1 = (k0 + 1 < 95);
    float a0 = 0.f, a1 = 0.f, f0 = 1.f, f1 = 1.f;
    if (v0) {
        float dens = softplusf(0.5f * (sg0 + sg1) - 1.0f);
        a0 = 1.0f - __expf(-dens * (d1 - d0));
        f0 = 1.0f - a0 + 1e-10f;
    }
    if (v1) {
        float dens = softplusf(0.5f * (sg1 + sg2) - 1.0f);
        a1 = 1.0f - __expf(-dens * (d2 - d1));
        f1 = 1.0f - a1 + 1e-10f;
    }

    float pl = f0 * f1;
    float x = pl;
#pragma unroll
    for (int d = 1; d < 64; d <<= 1) {
        float t = __shfl_up(x, d, 64);
        if (lane >= d) x *= t;
    }
    float excl = __shfl_up(x, 1, 64);
    if (lane == 0) excl = 1.0f;
    float w0 = a0 * excl;
    float w1 = a1 * excl * f0;

    float accR = w0 * 0.5f * (r0 + r1) + w1 * 0.5f * (r1 + r2);
    float accG = w0 * 0.5f * (g0 + g1) + w1 * 0.5f * (g1 + g2);
    float accB = w0 * 0.5f * (bb0 + bb1) + w1 * 0.5f * (bb1 + bb2);
    float accD = w0 * 0.5f * (d0 + d1) + w1 * 0.5f * (d1 + d2);
    float accW = w0 + w1;
#pragma unroll
    for (int mask = 1; mask <= 32; mask <<= 1) {
        accR += __shfl_xor(accR, mask, 64);
        accG += __shfl_xor(accG, mask, 64);
        accB += __shfl_xor(accB, mask, 64);
        accD += __shfl_xor(accD, mask, 64);
        accW += __shfl_xor(accW, mask, 64);
    }

    // global clip bounds from 16 partials (no atomics anywhere)
    float pmn = (lane < 16) ? part_mn[lane] : INFINITY;
    float pmx = (lane < 16) ? part_mx[lane] : -INFINITY;
#pragma unroll
    for (int mask = 1; mask <= 32; mask <<= 1) {
        pmn = fminf(pmn, __shfl_xor(pmn, mask, 64));
        pmx = fmaxf(pmx, __shfl_xor(pmx, mask, 64));
    }

    if (lane == 0) {
        float q = accD / accW;
        if (!isfinite(q)) q = 0.0f;
        q = fminf(fmaxf(q, pmn), pmx);
        out[ray * 3 + 0] = accR * 2.0f - 1.0f;
        out[ray * 3 + 1] = accG * 2.0f - 1.0f;
        out[ray * 3 + 2] = accB * 2.0f - 1.0f;
        out[3 * NRAY + ray] = q;
        out[4 * NRAY + ray] = accW;
    }
}

extern "C" void kernel_launch(void* const* d_in, const int* in_sizes, int n_in,
                              void* d_out, int out_size, void* d_ws, size_t ws_size,
                              hipStream_t stream)
{
    const float* planes_tex = (const float*)d_in[0];
    const float* planes_shp = (const float*)d_in[1];
    const float* origins    = (const float*)d_in[2];
    const float* raydirs    = (const float*)d_in[3];
    const float* W1 = (const float*)d_in[4];
    const float* b1 = (const float*)d_in[5];
    const float* W2 = (const float*)d_in[6];
    const float* b2 = (const float*)d_in[7];
    const float* noise = (const float*)d_in[8];
    const float* impu  = (const float*)d_in[9];
    float* out = (float*)d_out;

    char* ws = (char*)d_ws;
    __half*         planes_cl = (__half*)ws;                          // 50,331,648 B
    unsigned short* w1f       = (unsigned short*)(ws + 50331648);     // 8,192 B
    float*          w2f       = (float*)(ws + 50339840);              // 4,096 B
    float*          b1f       = (float*)(ws + 50343936);              // 1,024 B
    float*          part_mn   = (float*)(ws + 50344960);              // 64 B
    float*          part_mx   = (float*)(ws + 50345024);              // 64 B
    float*  depths_c = (float*)(ws + 50345216);                       // 1,572,864 B
    float*  depths_f = (float*)(ws + 51918080);                       // 1,572,864 B
    float4* rgbs_c   = (float4*)(ws + 53490944);                      // 6,291,456 B
    float4* rgbs_f   = (float4*)(ws + 59782400);                      // 6,291,456 B

    setup_kernel<<<dim3(TR_BLOCKS + 1 + 16), dim3(256), 0, stream>>>(
        planes_tex, planes_shp, planes_cl, W1, b1, W2, w1f, w2f, b1f, part_mn, part_mx, noise);

    fused_sample_mlp<false><<<dim3(NPTS / 32), dim3(256), 0, stream>>>(
        planes_cl, origins, raydirs, noise, nullptr, nullptr, nullptr,
        depths_c, w1f, w2f, b1f, b2, rgbs_c);

    fused_sample_mlp<true><<<dim3(NPTS / 32), dim3(256), 0, stream>>>(
        planes_cl, origins, raydirs, nullptr, impu, depths_c, rgbs_c,
        depths_f, w1f, w2f, b1f, b2, rgbs_f);

    final_march<<<dim3(NRAY / FM_WAVES), dim3(256), 0, stream>>>(
        depths_c, rgbs_c, depths_f, rgbs_f, part_mn, part_mx, out);
}